// Round 2
// baseline (787.529 us; speedup 1.0000x reference)
//
#include <hip/hip_runtime.h>
#include <stdint.h>

// Problem constants (fixed by reference): B=8192 samples, D=512 dims, 100 classes.
#define BSZ   8192
#define DIM   512

// ---------------------------------------------------------------------------
// Threefry-2x32-20 (exact JAX semantics). Rot consts {13,15,26,6},{17,29,16,24}
// ---------------------------------------------------------------------------
__host__ __device__ inline uint32_t rotl32(uint32_t v, int s) {
  return (v << s) | (v >> (32 - s));
}

__host__ __device__ inline void threefry2x32(uint32_t k0, uint32_t k1,
                                             uint32_t x0, uint32_t x1,
                                             uint32_t& o0, uint32_t& o1) {
  uint32_t ks2 = k0 ^ k1 ^ 0x1BD11BDAu;
  x0 += k0; x1 += k1;
  x0 += x1; x1 = rotl32(x1, 13); x1 ^= x0;
  x0 += x1; x1 = rotl32(x1, 15); x1 ^= x0;
  x0 += x1; x1 = rotl32(x1, 26); x1 ^= x0;
  x0 += x1; x1 = rotl32(x1,  6); x1 ^= x0;
  x0 += k1; x1 += ks2 + 1u;
  x0 += x1; x1 = rotl32(x1, 17); x1 ^= x0;
  x0 += x1; x1 = rotl32(x1, 29); x1 ^= x0;
  x0 += x1; x1 = rotl32(x1, 16); x1 ^= x0;
  x0 += x1; x1 = rotl32(x1, 24); x1 ^= x0;
  x0 += ks2; x1 += k0 + 2u;
  x0 += x1; x1 = rotl32(x1, 13); x1 ^= x0;
  x0 += x1; x1 = rotl32(x1, 15); x1 ^= x0;
  x0 += x1; x1 = rotl32(x1, 26); x1 ^= x0;
  x0 += x1; x1 = rotl32(x1,  6); x1 ^= x0;
  x0 += k0; x1 += k1 + 3u;
  x0 += x1; x1 = rotl32(x1, 17); x1 ^= x0;
  x0 += x1; x1 = rotl32(x1, 29); x1 ^= x0;
  x0 += x1; x1 = rotl32(x1, 16); x1 ^= x0;
  x0 += x1; x1 = rotl32(x1, 24); x1 ^= x0;
  x0 += k1; x1 += ks2 + 4u;
  x0 += x1; x1 = rotl32(x1, 13); x1 ^= x0;
  x0 += x1; x1 = rotl32(x1, 15); x1 ^= x0;
  x0 += x1; x1 = rotl32(x1, 26); x1 ^= x0;
  x0 += x1; x1 = rotl32(x1,  6); x1 ^= x0;
  x0 += ks2; x1 += k0 + 5u;
  o0 = x0; o1 = x1;
}

// ---------------------------------------------------------------------------
// Workspace layout (bytes)
// ---------------------------------------------------------------------------
constexpr size_t OFF_ACC  = 0;                               // 2 floats: loss sum, n_valid
constexpr size_t OFF_S    = 1024;                            // 512 f32 column sums
constexpr size_t OFF_M    = 4096;                            // 512x512 f32 = F^T F
constexpr size_t OFF_G    = OFF_M    + (size_t)DIM * DIM * 4;  // 512x512 f32 metric
constexpr size_t OFF_PIDX = OFF_G    + (size_t)DIM * DIM * 4;  // 8192 int
constexpr size_t OFF_NIDX = OFF_PIDX + (size_t)BSZ * 4;        // 8192 int
constexpr size_t OFF_H    = OFF_NIDX + (size_t)BSZ * 4;        // 8192x512 f32 = F*G
constexpr size_t ZERO_BYTES = OFF_M + (size_t)DIM * DIM * 4;   // zero acc+S+M

// ---------------------------------------------------------------------------
// Kernel 1: column sums S[d] = sum_b F[b][d]
// ---------------------------------------------------------------------------
__global__ __launch_bounds__(256) void colsum_kernel(const float* __restrict__ F,
                                                     float* __restrict__ S) {
  int b0 = blockIdx.x * 32;   // 32 rows per block, 256 blocks
  int t = threadIdx.x;
  float s0 = 0.f, s1 = 0.f;
  for (int r = 0; r < 32; ++r) {
    const float* row = F + (size_t)(b0 + r) * DIM;
    s0 += row[t];
    s1 += row[t + 256];
  }
  atomicAdd(&S[t], s0);
  atomicAdd(&S[t + 256], s1);
}

// ---------------------------------------------------------------------------
// Kernel 2: M = F^T F, 32x32 output tiles, K-split with atomics
// grid (16,16,4), block 256
// ---------------------------------------------------------------------------
__global__ __launch_bounds__(256) void covmat_kernel(const float* __restrict__ F,
                                                     float* __restrict__ M) {
  __shared__ float sA[64][33];
  __shared__ float sB[64][33];
  int i0 = blockIdx.x * 32;
  int j0 = blockIdx.y * 32;
  int k0 = blockIdx.z * 2048;
  int tid = threadIdx.x;
  int tx = tid & 15, ty = tid >> 4;
  float acc00 = 0.f, acc01 = 0.f, acc10 = 0.f, acc11 = 0.f;
  for (int kk = 0; kk < 2048; kk += 64) {
    for (int r = 0; r < 8; ++r) {
      int idx = tid + 256 * r;
      int lr = idx >> 5, lc = idx & 31;
      size_t rowoff = (size_t)(k0 + kk + lr) * DIM;
      sA[lr][lc] = F[rowoff + i0 + lc];
      sB[lr][lc] = F[rowoff + j0 + lc];
    }
    __syncthreads();
    for (int k = 0; k < 64; ++k) {
      float a0 = sA[k][tx * 2], a1 = sA[k][tx * 2 + 1];
      float b0 = sB[k][ty * 2], b1 = sB[k][ty * 2 + 1];
      acc00 += a0 * b0; acc01 += a0 * b1;
      acc10 += a1 * b0; acc11 += a1 * b1;
    }
    __syncthreads();
  }
  int i = i0 + tx * 2, j = j0 + ty * 2;
  atomicAdd(&M[(size_t)i * DIM + j], acc00);
  atomicAdd(&M[(size_t)i * DIM + j + 1], acc01);
  atomicAdd(&M[(size_t)(i + 1) * DIM + j], acc10);
  atomicAdd(&M[(size_t)(i + 1) * DIM + j + 1], acc11);
}

// ---------------------------------------------------------------------------
// Kernel 3: G = M/B - mean mean^T + I
// ---------------------------------------------------------------------------
__global__ __launch_bounds__(256) void buildG_kernel(const float* __restrict__ M,
                                                     const float* __restrict__ S,
                                                     float* __restrict__ G) {
  int idx = blockIdx.x * 256 + threadIdx.x;   // 1024 blocks covers 512*512
  int i = idx >> 9, j = idx & 511;
  const float invB = 1.0f / (float)BSZ;
  float mi = S[i] * invB, mj = S[j] * invB;
  G[idx] = M[idx] * invB - mi * mj + (i == j ? 1.0f : 0.0f);
}

// ---------------------------------------------------------------------------
// Kernel 4: H = F * G   (8192x512 = 8192x512 @ 512x512)
// grid (8, 128), block 256, 64x64 tiles, 4x4 per thread
// ---------------------------------------------------------------------------
__global__ __launch_bounds__(256) void matmulH_kernel(const float* __restrict__ F,
                                                      const float* __restrict__ G,
                                                      float* __restrict__ H) {
  __shared__ float sF[64][33];   // [m][k]
  __shared__ float sG[32][65];   // [k][n]
  int n0 = blockIdx.x * 64;
  int m0 = blockIdx.y * 64;
  int tid = threadIdx.x;
  int tn = (tid & 15) * 4;
  int tm = (tid >> 4) * 4;
  float acc[4][4] = {};
  for (int k0 = 0; k0 < DIM; k0 += 32) {
    for (int r = 0; r < 8; ++r) {
      int idx = tid + 256 * r;
      int lr = idx >> 5, lc = idx & 31;
      sF[lr][lc] = F[(size_t)(m0 + lr) * DIM + k0 + lc];
    }
    for (int r = 0; r < 8; ++r) {
      int idx = tid + 256 * r;
      int lr = idx >> 6, lc = idx & 63;
      sG[lr][lc] = G[(size_t)(k0 + lr) * DIM + n0 + lc];
    }
    __syncthreads();
    for (int k = 0; k < 32; ++k) {
      float a[4], b[4];
#pragma unroll
      for (int x = 0; x < 4; ++x) { a[x] = sF[tm + x][k]; b[x] = sG[k][tn + x]; }
#pragma unroll
      for (int x = 0; x < 4; ++x)
#pragma unroll
        for (int y = 0; y < 4; ++y) acc[x][y] += a[x] * b[y];
    }
    __syncthreads();
  }
  for (int x = 0; x < 4; ++x)
    for (int y = 0; y < 4; ++y)
      H[(size_t)(m0 + tm + x) * DIM + n0 + tn + y] = acc[x][y];
}

// ---------------------------------------------------------------------------
// Kernel 5: gumbel-max argmax via PARTITIONABLE threefry (JAX >= 0.4.30
// default). Element (r,c) of the [B,B] uniform draw uses counter
// (hi,lo) = (0, r*B+c) and 32-bit output y0 ^ y1. Gumbel-max over the row
// == argmax of (bits >> 9) with FIRST-index tie-break (monotone transform);
// composite key (u23 << 32) | ~c implements that under unsigned max.
// comp==0 <=> no valid candidate. One block per row.
// ---------------------------------------------------------------------------
__device__ unsigned long long block_max_u64(unsigned long long v,
                                            unsigned long long* sred) {
  int tid = threadIdx.x;
  sred[tid] = v;
  __syncthreads();
  for (int s = 128; s > 0; s >>= 1) {
    if (tid < s) {
      unsigned long long o = sred[tid + s];
      if (o > sred[tid]) sred[tid] = o;
    }
    __syncthreads();
  }
  unsigned long long r = sred[0];
  __syncthreads();
  return r;
}

__global__ __launch_bounds__(256) void argmax_kernel(const int* __restrict__ labels,
                                                     uint32_t kp0, uint32_t kp1,
                                                     uint32_t kn0, uint32_t kn1,
                                                     int* __restrict__ posIdx,
                                                     int* __restrict__ negIdx) {
  __shared__ unsigned long long sred[256];
  int i = blockIdx.x;
  int li = labels[i];
  unsigned long long bP = 0, bN = 0;
  for (int c = threadIdx.x; c < BSZ; c += 256) {
    int lc = labels[c];
    uint32_t x1 = (uint32_t)(i * BSZ + c);   // flat index < 2^26, hi word = 0
    unsigned long long tail = (unsigned long long)(~(uint32_t)c);
    if (lc == li) {
      // positive candidate (skipped by exec-mask when no lane needs it)
      if (c != i) {
        uint32_t a0, a1;
        threefry2x32(kp0, kp1, 0u, x1, a0, a1);
        uint32_t bits = a0 ^ a1;
        unsigned long long comp = ((unsigned long long)(bits >> 9) << 32) | tail;
        if (comp > bP) bP = comp;
      }
    } else {
      uint32_t b0, b1;
      threefry2x32(kn0, kn1, 0u, x1, b0, b1);
      uint32_t bits = b0 ^ b1;
      unsigned long long comp = ((unsigned long long)(bits >> 9) << 32) | tail;
      if (comp > bN) bN = comp;
    }
  }
  unsigned long long r;
  r = block_max_u64(bP, sred);
  if (threadIdx.x == 0) posIdx[i] = r ? (int)(~(uint32_t)(r & 0xFFFFFFFFull)) : -1;
  r = block_max_u64(bN, sred);
  if (threadIdx.x == 0) negIdx[i] = r ? (int)(~(uint32_t)(r & 0xFFFFFFFFull)) : -1;
}

// ---------------------------------------------------------------------------
// Kernel 6: per-row loss. d^2(i,j) = q_ii + q_jj - 2 q_ij with q_ij = F[i].H[j]
// One wave per row (4 rows per 256-thread block).
// ---------------------------------------------------------------------------
__global__ __launch_bounds__(256) void loss_kernel(const float* __restrict__ F,
                                                   const float* __restrict__ H,
                                                   const int* __restrict__ posIdx,
                                                   const int* __restrict__ negIdx,
                                                   float* __restrict__ acc) {
  int row = blockIdx.x * 4 + (threadIdx.x >> 6);
  int lane = threadIdx.x & 63;
  int p = posIdx[row], n = negIdx[row];
  bool valid = (p >= 0) && (n >= 0);
  int ps = valid ? p : row;
  int ns = valid ? n : row;
  const float* Fi = F + (size_t)row * DIM;
  const float* Hi = H + (size_t)row * DIM;
  const float* Fp = F + (size_t)ps * DIM;
  const float* Hp = H + (size_t)ps * DIM;
  const float* Fn = F + (size_t)ns * DIM;
  const float* Hn = H + (size_t)ns * DIM;
  float qii = 0.f, qpp = 0.f, qip = 0.f, qnn = 0.f, qin = 0.f;
  for (int k = lane; k < DIM; k += 64) {
    float fi = Fi[k], hi = Hi[k];
    float fp = Fp[k], hp = Hp[k];
    float fn = Fn[k], hn = Hn[k];
    qii += fi * hi;
    qpp += fp * hp;
    qip += fi * hp;
    qnn += fn * hn;
    qin += fi * hn;
  }
#pragma unroll
  for (int off = 32; off > 0; off >>= 1) {
    qii += __shfl_down(qii, off);
    qpp += __shfl_down(qpp, off);
    qip += __shfl_down(qip, off);
    qnn += __shfl_down(qnn, off);
    qin += __shfl_down(qin, off);
  }
  if (lane == 0) {
    float d2p = fmaxf(qii + qpp - 2.f * qip, 0.f);
    float d2n = fmaxf(qii + qnn - 2.f * qin, 0.f);
    float dpos = sqrtf(d2p + 1e-8f);
    float dneg = sqrtf(d2n + 1e-8f);
    float v = fmaxf(dpos - dneg + 1.0f, 0.0f);
    if (!valid) v = 0.f;
    atomicAdd(&acc[0], v);
    if (valid) atomicAdd(&acc[1], 1.0f);
  }
}

// ---------------------------------------------------------------------------
// Kernel 7: finalize
// ---------------------------------------------------------------------------
__global__ void finalize_kernel(const float* __restrict__ acc, float* __restrict__ out) {
  out[0] = acc[0] / fmaxf(acc[1], 1.0f);
}

// ---------------------------------------------------------------------------
extern "C" void kernel_launch(void* const* d_in, const int* in_sizes, int n_in,
                              void* d_out, int out_size, void* d_ws, size_t ws_size,
                              hipStream_t stream) {
  const float* F = (const float*)d_in[0];
  const int* labels = (const int*)d_in[1];
  float* out = (float*)d_out;
  char* ws = (char*)d_ws;

  float* acc  = (float*)(ws + OFF_ACC);
  float* S    = (float*)(ws + OFF_S);
  float* M    = (float*)(ws + OFF_M);
  float* G    = (float*)(ws + OFF_G);
  int* posIdx = (int*)(ws + OFF_PIDX);
  int* negIdx = (int*)(ws + OFF_NIDX);
  float* H    = (float*)(ws + OFF_H);

  // Partitionable (foldlike) split of jax.random.key(42):
  // kp = threefry((0,42), (0,0)), kn = threefry((0,42), (0,1))
  uint32_t kp0, kp1, kn0, kn1;
  threefry2x32(0u, 42u, 0u, 0u, kp0, kp1);
  threefry2x32(0u, 42u, 0u, 1u, kn0, kn1);

  hipMemsetAsync(ws, 0, ZERO_BYTES, stream);

  colsum_kernel<<<256, 256, 0, stream>>>(F, S);

  dim3 covGrid(16, 16, 4);
  covmat_kernel<<<covGrid, 256, 0, stream>>>(F, M);

  buildG_kernel<<<(DIM * DIM) / 256, 256, 0, stream>>>(M, S, G);

  dim3 hGrid(DIM / 64, BSZ / 64);
  matmulH_kernel<<<hGrid, 256, 0, stream>>>(F, G, H);

  argmax_kernel<<<BSZ, 256, 0, stream>>>(labels, kp0, kp1, kn0, kn1, posIdx, negIdx);

  loss_kernel<<<BSZ / 4, 256, 0, stream>>>(F, H, posIdx, negIdx, acc);

  finalize_kernel<<<1, 1, 0, stream>>>(acc, out);
}

// Round 3
// 595.834 us; speedup vs baseline: 1.3217x; 1.3217x over previous
//
#include <hip/hip_runtime.h>
#include <stdint.h>

// Problem constants (fixed by reference): B=8192 samples, D=512 dims, 100 classes.
#define BSZ   8192
#define DIM   512

// ---------------------------------------------------------------------------
// Threefry-2x32-20 (exact JAX semantics, partitionable mode: bits = y0 ^ y1).
// rotl compiles to v_alignbit_b32 (1 instr).
// ---------------------------------------------------------------------------
__host__ __device__ inline uint32_t rotl32(uint32_t v, int s) {
#if defined(__HIP_DEVICE_COMPILE__) && __has_builtin(__builtin_amdgcn_alignbit)
  return __builtin_amdgcn_alignbit(v, v, 32 - s);
#else
  return (v << s) | (v >> (32 - s));
#endif
}

__host__ __device__ inline void threefry2x32(uint32_t k0, uint32_t k1,
                                             uint32_t x0, uint32_t x1,
                                             uint32_t& o0, uint32_t& o1) {
  uint32_t ks2 = k0 ^ k1 ^ 0x1BD11BDAu;
  x0 += k0; x1 += k1;
  x0 += x1; x1 = rotl32(x1, 13); x1 ^= x0;
  x0 += x1; x1 = rotl32(x1, 15); x1 ^= x0;
  x0 += x1; x1 = rotl32(x1, 26); x1 ^= x0;
  x0 += x1; x1 = rotl32(x1,  6); x1 ^= x0;
  x0 += k1; x1 += ks2 + 1u;
  x0 += x1; x1 = rotl32(x1, 17); x1 ^= x0;
  x0 += x1; x1 = rotl32(x1, 29); x1 ^= x0;
  x0 += x1; x1 = rotl32(x1, 16); x1 ^= x0;
  x0 += x1; x1 = rotl32(x1, 24); x1 ^= x0;
  x0 += ks2; x1 += k0 + 2u;
  x0 += x1; x1 = rotl32(x1, 13); x1 ^= x0;
  x0 += x1; x1 = rotl32(x1, 15); x1 ^= x0;
  x0 += x1; x1 = rotl32(x1, 26); x1 ^= x0;
  x0 += x1; x1 = rotl32(x1,  6); x1 ^= x0;
  x0 += k0; x1 += k1 + 3u;
  x0 += x1; x1 = rotl32(x1, 17); x1 ^= x0;
  x0 += x1; x1 = rotl32(x1, 29); x1 ^= x0;
  x0 += x1; x1 = rotl32(x1, 16); x1 ^= x0;
  x0 += x1; x1 = rotl32(x1, 24); x1 ^= x0;
  x0 += k1; x1 += ks2 + 4u;
  x0 += x1; x1 = rotl32(x1, 13); x1 ^= x0;
  x0 += x1; x1 = rotl32(x1, 15); x1 ^= x0;
  x0 += x1; x1 = rotl32(x1, 26); x1 ^= x0;
  x0 += x1; x1 = rotl32(x1,  6); x1 ^= x0;
  x0 += ks2; x1 += k0 + 5u;
  o0 = x0; o1 = x1;
}

// ---------------------------------------------------------------------------
// Workspace layout (bytes). Total 18,874,368 B — under the proven 18.9 MB.
// Mpart (16 x 1 MB split-K partials of F^T F) ALIASES the H region: it is
// consumed by buildG before matmulH writes H.
// ---------------------------------------------------------------------------
constexpr size_t OFF_ACC    = 0;         // 2 floats
constexpr size_t OFF_S      = 1024;      // 512 f32 column sums
constexpr size_t OFF_BSTART = 3072;      // 101 ints: class bucket starts
constexpr size_t OFF_BIDX   = 4096;      // 8192 ints: rows grouped by class
constexpr size_t OFF_PIDX   = 36864;     // 8192 ints
constexpr size_t OFF_NIDX   = 69632;     // 8192 ints
constexpr size_t OFF_G      = 131072;    // 512x512 f32 metric
constexpr size_t OFF_H      = 2097152;   // 8192x512 f32 = F*G (16 MB)
constexpr size_t ZERO_BYTES = 3072;      // acc + S

// ---------------------------------------------------------------------------
// Kernel 1: column sums S[d] = sum_b F[b][d]
// ---------------------------------------------------------------------------
__global__ __launch_bounds__(256) void colsum_kernel(const float* __restrict__ F,
                                                     float* __restrict__ S) {
  int b0 = blockIdx.x * 32;
  int t = threadIdx.x;
  float s0 = 0.f, s1 = 0.f;
  for (int r = 0; r < 32; ++r) {
    const float* row = F + (size_t)(b0 + r) * DIM;
    s0 += row[t];
    s1 += row[t + 256];
  }
  atomicAdd(&S[t], s0);
  atomicAdd(&S[t + 256], s1);
}

// ---------------------------------------------------------------------------
// Kernel 2: Mpart[z] = F[z-chunk]^T F[z-chunk], 128x64 tile, 8x4 frag, b128.
// grid (4, 8, 16), block 256. F is [k][i] so both LDS tiles stage w/o transpose.
// ---------------------------------------------------------------------------
__global__ __launch_bounds__(256) void covmat_kernel(const float* __restrict__ F,
                                                     float* __restrict__ Mpart) {
  __shared__ float sA[32][132];   // [k][i] tile 32x128 (+4 pad)
  __shared__ float sB[32][68];    // [k][j] tile 32x64
  int i0 = blockIdx.x * 128;
  int j0 = blockIdx.y * 64;
  int k0 = blockIdx.z * 512;
  int tid = threadIdx.x;
  int ti = (tid >> 4) * 8;
  int tj = (tid & 15) * 4;
  float acc[8][4] = {};
  for (int kk = 0; kk < 512; kk += 32) {
#pragma unroll
    for (int r = 0; r < 4; ++r) {          // stage A: 1024 float4
      int idx = tid + 256 * r;
      int lr = idx >> 5, lc = (idx & 31) * 4;
      *(float4*)&sA[lr][lc] = *(const float4*)&F[(size_t)(k0 + kk + lr) * DIM + i0 + lc];
    }
#pragma unroll
    for (int r = 0; r < 2; ++r) {          // stage B: 512 float4
      int idx = tid + 256 * r;
      int lr = idx >> 4, lc = (idx & 15) * 4;
      *(float4*)&sB[lr][lc] = *(const float4*)&F[(size_t)(k0 + kk + lr) * DIM + j0 + lc];
    }
    __syncthreads();
#pragma unroll
    for (int k = 0; k < 32; ++k) {
      float4 a0 = *(float4*)&sA[k][ti];
      float4 a1 = *(float4*)&sA[k][ti + 4];
      float4 b  = *(float4*)&sB[k][tj];
      float a[8] = {a0.x, a0.y, a0.z, a0.w, a1.x, a1.y, a1.z, a1.w};
      float bb[4] = {b.x, b.y, b.z, b.w};
#pragma unroll
      for (int x = 0; x < 8; ++x)
#pragma unroll
        for (int y = 0; y < 4; ++y) acc[x][y] += a[x] * bb[y];
    }
    __syncthreads();
  }
  float* out = Mpart + (size_t)blockIdx.z * DIM * DIM;
#pragma unroll
  for (int x = 0; x < 8; ++x) {
    float4 v = {acc[x][0], acc[x][1], acc[x][2], acc[x][3]};
    *(float4*)&out[(size_t)(i0 + ti + x) * DIM + j0 + tj] = v;
  }
}

// ---------------------------------------------------------------------------
// Kernel 3: G = (sum_z Mpart[z])/B - mean mean^T + I
// ---------------------------------------------------------------------------
__global__ __launch_bounds__(256) void buildG_kernel(const float* __restrict__ Mpart,
                                                     const float* __restrict__ S,
                                                     float* __restrict__ G) {
  int idx = blockIdx.x * 256 + threadIdx.x;
  int i = idx >> 9, j = idx & 511;
  float m = 0.f;
#pragma unroll
  for (int z = 0; z < 16; ++z) m += Mpart[(size_t)z * DIM * DIM + idx];
  const float invB = 1.0f / (float)BSZ;
  float mi = S[i] * invB, mj = S[j] * invB;
  G[idx] = m * invB - mi * mj + (i == j ? 1.0f : 0.0f);
}

// ---------------------------------------------------------------------------
// Kernel 4: H = F * G. 128(m)x64(n) tile, 8x4 frag. A staged [m][k] (direct
// float4 copy, k-blocked b128 reads), B staged [k][n]. grid (8, 64), block 256.
// ---------------------------------------------------------------------------
__global__ __launch_bounds__(256) void matmulH_kernel(const float* __restrict__ F,
                                                      const float* __restrict__ G,
                                                      float* __restrict__ H) {
  __shared__ float sF[128][36];   // [m][k] tile 128x32 (+4 pad; 144B row = 9x16)
  __shared__ float sG[32][68];    // [k][n] tile 32x64
  int n0 = blockIdx.x * 64;
  int m0 = blockIdx.y * 128;
  int tid = threadIdx.x;
  int tm = (tid >> 4) * 8;
  int tn = (tid & 15) * 4;
  float acc[8][4] = {};
  for (int k0 = 0; k0 < DIM; k0 += 32) {
#pragma unroll
    for (int r = 0; r < 4; ++r) {          // stage F: 1024 float4 (no transpose)
      int idx = tid + 256 * r;
      int mm = idx >> 3, kk = (idx & 7) * 4;
      *(float4*)&sF[mm][kk] = *(const float4*)&F[(size_t)(m0 + mm) * DIM + k0 + kk];
    }
#pragma unroll
    for (int r = 0; r < 2; ++r) {          // stage G: 512 float4
      int idx = tid + 256 * r;
      int lr = idx >> 4, lc = (idx & 15) * 4;
      *(float4*)&sG[lr][lc] = *(const float4*)&G[(size_t)(k0 + lr) * DIM + n0 + lc];
    }
    __syncthreads();
#pragma unroll
    for (int k4 = 0; k4 < 32; k4 += 4) {
      float4 a[8];
#pragma unroll
      for (int x = 0; x < 8; ++x) a[x] = *(float4*)&sF[tm + x][k4];
      float4 b[4];
#pragma unroll
      for (int j = 0; j < 4; ++j) b[j] = *(float4*)&sG[k4 + j][tn];
#pragma unroll
      for (int x = 0; x < 8; ++x) {
        float ax[4] = {a[x].x, a[x].y, a[x].z, a[x].w};
#pragma unroll
        for (int j = 0; j < 4; ++j) {
          float bj[4] = {b[j].x, b[j].y, b[j].z, b[j].w};
#pragma unroll
          for (int y = 0; y < 4; ++y) acc[x][y] += ax[j] * bj[y];
        }
      }
    }
    __syncthreads();
  }
#pragma unroll
  for (int x = 0; x < 8; ++x) {
    float4 v = {acc[x][0], acc[x][1], acc[x][2], acc[x][3]};
    *(float4*)&H[(size_t)(m0 + tm + x) * DIM + n0 + tn] = v;
  }
}

// ---------------------------------------------------------------------------
// Kernel 5: class buckets (single block). bucketStart[c]..bucketStart[c+1]
// spans bucketIdx entries of class c (order within bucket irrelevant: the
// composite max is order-independent).
// ---------------------------------------------------------------------------
__global__ __launch_bounds__(256) void bucket_kernel(const int* __restrict__ labels,
                                                     int* __restrict__ bucketStart,
                                                     int* __restrict__ bucketIdx) {
  __shared__ int cnt[128];
  __shared__ int base[128];
  int tid = threadIdx.x;
  if (tid < 128) cnt[tid] = 0;
  __syncthreads();
  for (int b = tid; b < BSZ; b += 256) atomicAdd(&cnt[labels[b]], 1);
  __syncthreads();
  if (tid == 0) {
    int run = 0;
    for (int c = 0; c < 100; ++c) { base[c] = run; bucketStart[c] = run; run += cnt[c]; }
    bucketStart[100] = run;
  }
  __syncthreads();
  for (int b = tid; b < BSZ; b += 256) {
    int p = atomicAdd(&base[labels[b]], 1);
    bucketIdx[p] = b;
  }
}

// ---------------------------------------------------------------------------
// Kernel 6: negative argmax — UNIFORM pass, one block per row. Every lane
// hashes every column (no divergence); same-class candidates are cndmask'd
// to 0. Composite (bits23<<32)|~c == gumbel argmax w/ first-index tie-break.
// ---------------------------------------------------------------------------
__global__ __launch_bounds__(256) void negmax_kernel(const int* __restrict__ labels,
                                                     uint32_t kn0, uint32_t kn1,
                                                     int* __restrict__ negIdx) {
  __shared__ unsigned long long wmax[4];
  int i = blockIdx.x;
  int li = labels[i];
  uint32_t base = (uint32_t)(i << 13);
  unsigned long long best = 0;
  int c = threadIdx.x;
#pragma unroll 2
  for (int it = 0; it < 32; ++it, c += 256) {
    int lc = labels[c];
    uint32_t a0, a1;
    threefry2x32(kn0, kn1, 0u, base + (uint32_t)c, a0, a1);
    uint32_t bits = (a0 ^ a1) >> 9;
    unsigned long long comp = ((unsigned long long)bits << 32) | (uint32_t)(~c);
    if (lc == li) comp = 0;
    if (comp > best) best = comp;
  }
#pragma unroll
  for (int off = 32; off; off >>= 1) {
    unsigned long long o = __shfl_down(best, off);
    if (o > best) best = o;
  }
  int wid = threadIdx.x >> 6;
  if ((threadIdx.x & 63) == 0) wmax[wid] = best;
  __syncthreads();
  if (threadIdx.x == 0) {
    best = wmax[0];
    for (int w = 1; w < 4; ++w) if (wmax[w] > best) best = wmax[w];
    negIdx[i] = best ? (int)(~(uint32_t)best) : -1;
  }
}

// ---------------------------------------------------------------------------
// Kernel 7: positive argmax — bucketed. One wave per row over its own class
// bucket (~82 entries). grid 2048, block 256 (4 rows/block).
// ---------------------------------------------------------------------------
__global__ __launch_bounds__(256) void posmax_kernel(const int* __restrict__ labels,
                                                     const int* __restrict__ bucketStart,
                                                     const int* __restrict__ bucketIdx,
                                                     uint32_t kp0, uint32_t kp1,
                                                     int* __restrict__ posIdx) {
  int row = blockIdx.x * 4 + (threadIdx.x >> 6);
  int lane = threadIdx.x & 63;
  int cls = labels[row];
  int s = bucketStart[cls], e = bucketStart[cls + 1];
  uint32_t base = (uint32_t)(row << 13);
  unsigned long long best = 0;
  for (int t = s + lane; t < e; t += 64) {
    int cc = bucketIdx[t];
    uint32_t a0, a1;
    threefry2x32(kp0, kp1, 0u, base + (uint32_t)cc, a0, a1);
    uint32_t bits = (a0 ^ a1) >> 9;
    unsigned long long comp = ((unsigned long long)bits << 32) | (uint32_t)(~cc);
    if (cc == row) comp = 0;
    if (comp > best) best = comp;
  }
#pragma unroll
  for (int off = 32; off; off >>= 1) {
    unsigned long long o = __shfl_down(best, off);
    if (o > best) best = o;
  }
  if (lane == 0) posIdx[row] = best ? (int)(~(uint32_t)best) : -1;
}

// ---------------------------------------------------------------------------
// Kernel 8: per-row loss. d^2(i,j) = q_ii + q_jj - 2 q_ij, q_ij = F[i].H[j].
// One wave per row, float4 loads.
// ---------------------------------------------------------------------------
__global__ __launch_bounds__(256) void loss_kernel(const float* __restrict__ F,
                                                   const float* __restrict__ H,
                                                   const int* __restrict__ posIdx,
                                                   const int* __restrict__ negIdx,
                                                   float* __restrict__ acc) {
  int row = blockIdx.x * 4 + (threadIdx.x >> 6);
  int lane = threadIdx.x & 63;
  int p = posIdx[row], n = negIdx[row];
  bool valid = (p >= 0) && (n >= 0);
  int ps = valid ? p : row;
  int ns = valid ? n : row;
  const float* Fi = F + (size_t)row * DIM;
  const float* Hi = H + (size_t)row * DIM;
  const float* Fp = F + (size_t)ps * DIM;
  const float* Hp = H + (size_t)ps * DIM;
  const float* Fn = F + (size_t)ns * DIM;
  const float* Hn = H + (size_t)ns * DIM;
  float qii = 0.f, qpp = 0.f, qip = 0.f, qnn = 0.f, qin = 0.f;
#pragma unroll
  for (int k = lane * 4; k < DIM; k += 256) {
    float4 fi = *(const float4*)&Fi[k], hi = *(const float4*)&Hi[k];
    float4 fp = *(const float4*)&Fp[k], hp = *(const float4*)&Hp[k];
    float4 fn = *(const float4*)&Fn[k], hn = *(const float4*)&Hn[k];
    qii += fi.x * hi.x + fi.y * hi.y + fi.z * hi.z + fi.w * hi.w;
    qpp += fp.x * hp.x + fp.y * hp.y + fp.z * hp.z + fp.w * hp.w;
    qip += fi.x * hp.x + fi.y * hp.y + fi.z * hp.z + fi.w * hp.w;
    qnn += fn.x * hn.x + fn.y * hn.y + fn.z * hn.z + fn.w * hn.w;
    qin += fi.x * hn.x + fi.y * hn.y + fi.z * hn.z + fi.w * hn.w;
  }
#pragma unroll
  for (int off = 32; off > 0; off >>= 1) {
    qii += __shfl_down(qii, off);
    qpp += __shfl_down(qpp, off);
    qip += __shfl_down(qip, off);
    qnn += __shfl_down(qnn, off);
    qin += __shfl_down(qin, off);
  }
  if (lane == 0) {
    float d2p = fmaxf(qii + qpp - 2.f * qip, 0.f);
    float d2n = fmaxf(qii + qnn - 2.f * qin, 0.f);
    float dpos = sqrtf(d2p + 1e-8f);
    float dneg = sqrtf(d2n + 1e-8f);
    float v = fmaxf(dpos - dneg + 1.0f, 0.0f);
    if (!valid) v = 0.f;
    atomicAdd(&acc[0], v);
    if (valid) atomicAdd(&acc[1], 1.0f);
  }
}

// ---------------------------------------------------------------------------
__global__ void finalize_kernel(const float* __restrict__ acc, float* __restrict__ out) {
  out[0] = acc[0] / fmaxf(acc[1], 1.0f);
}

// ---------------------------------------------------------------------------
extern "C" void kernel_launch(void* const* d_in, const int* in_sizes, int n_in,
                              void* d_out, int out_size, void* d_ws, size_t ws_size,
                              hipStream_t stream) {
  const float* F = (const float*)d_in[0];
  const int* labels = (const int*)d_in[1];
  float* out = (float*)d_out;
  char* ws = (char*)d_ws;

  float* acc    = (float*)(ws + OFF_ACC);
  float* S      = (float*)(ws + OFF_S);
  int* bStart   = (int*)(ws + OFF_BSTART);
  int* bIdx     = (int*)(ws + OFF_BIDX);
  int* posIdx   = (int*)(ws + OFF_PIDX);
  int* negIdx   = (int*)(ws + OFF_NIDX);
  float* G      = (float*)(ws + OFF_G);
  float* H      = (float*)(ws + OFF_H);
  float* Mpart  = H;   // 16 x 1MB split-K partials, consumed before H is written

  // Partitionable (foldlike) split of jax.random.key(42):
  uint32_t kp0, kp1, kn0, kn1;
  threefry2x32(0u, 42u, 0u, 0u, kp0, kp1);
  threefry2x32(0u, 42u, 0u, 1u, kn0, kn1);

  hipMemsetAsync(ws, 0, ZERO_BYTES, stream);

  colsum_kernel<<<256, 256, 0, stream>>>(F, S);

  dim3 covGrid(4, 8, 16);
  covmat_kernel<<<covGrid, 256, 0, stream>>>(F, Mpart);

  buildG_kernel<<<(DIM * DIM) / 256, 256, 0, stream>>>(Mpart, S, G);

  bucket_kernel<<<1, 256, 0, stream>>>(labels, bStart, bIdx);

  negmax_kernel<<<BSZ, 256, 0, stream>>>(labels, kn0, kn1, negIdx);

  posmax_kernel<<<BSZ / 4, 256, 0, stream>>>(labels, bStart, bIdx, kp0, kp1, posIdx);

  dim3 hGrid(DIM / 64, BSZ / 128);
  matmulH_kernel<<<hGrid, 256, 0, stream>>>(F, G, H);

  loss_kernel<<<BSZ / 4, 256, 0, stream>>>(F, H, posIdx, negIdx, acc);

  finalize_kernel<<<1, 1, 0, stream>>>(acc, out);
}

// Round 7
// 411.417 us; speedup vs baseline: 1.9142x; 1.4482x over previous
//
#include <hip/hip_runtime.h>
#include <stdint.h>

// Problem constants (fixed by reference): B=8192 samples, D=512 dims, 100 classes.
#define BSZ   8192
#define DIM   512

// ---------------------------------------------------------------------------
// Threefry-2x32-20 (exact JAX semantics, partitionable mode: bits = y0 ^ y1).
// rotl compiles to v_alignbit_b32 (1 instr).
// ---------------------------------------------------------------------------
__host__ __device__ inline uint32_t rotl32(uint32_t v, int s) {
#if defined(__HIP_DEVICE_COMPILE__) && __has_builtin(__builtin_amdgcn_alignbit)
  return __builtin_amdgcn_alignbit(v, v, 32 - s);
#else
  return (v << s) | (v >> (32 - s));
#endif
}

__host__ __device__ inline void threefry2x32(uint32_t k0, uint32_t k1,
                                             uint32_t x0, uint32_t x1,
                                             uint32_t& o0, uint32_t& o1) {
  uint32_t ks2 = k0 ^ k1 ^ 0x1BD11BDAu;
  x0 += k0; x1 += k1;
  x0 += x1; x1 = rotl32(x1, 13); x1 ^= x0;
  x0 += x1; x1 = rotl32(x1, 15); x1 ^= x0;
  x0 += x1; x1 = rotl32(x1, 26); x1 ^= x0;
  x0 += x1; x1 = rotl32(x1,  6); x1 ^= x0;
  x0 += k1; x1 += ks2 + 1u;
  x0 += x1; x1 = rotl32(x1, 17); x1 ^= x0;
  x0 += x1; x1 = rotl32(x1, 29); x1 ^= x0;
  x0 += x1; x1 = rotl32(x1, 16); x1 ^= x0;
  x0 += x1; x1 = rotl32(x1, 24); x1 ^= x0;
  x0 += ks2; x1 += k0 + 2u;
  x0 += x1; x1 = rotl32(x1, 13); x1 ^= x0;
  x0 += x1; x1 = rotl32(x1, 15); x1 ^= x0;
  x0 += x1; x1 = rotl32(x1, 26); x1 ^= x0;
  x0 += x1; x1 = rotl32(x1,  6); x1 ^= x0;
  x0 += k0; x1 += k1 + 3u;
  x0 += x1; x1 = rotl32(x1, 17); x1 ^= x0;
  x0 += x1; x1 = rotl32(x1, 29); x1 ^= x0;
  x0 += x1; x1 = rotl32(x1, 16); x1 ^= x0;
  x0 += x1; x1 = rotl32(x1, 24); x1 ^= x0;
  x0 += k1; x1 += ks2 + 4u;
  x0 += x1; x1 = rotl32(x1, 13); x1 ^= x0;
  x0 += x1; x1 = rotl32(x1, 15); x1 ^= x0;
  x0 += x1; x1 = rotl32(x1, 26); x1 ^= x0;
  x0 += x1; x1 = rotl32(x1,  6); x1 ^= x0;
  x0 += ks2; x1 += k0 + 5u;
  o0 = x0; o1 = x1;
}

// ---------------------------------------------------------------------------
// Workspace layout (bytes) — IDENTICAL to the round-3 source that benched at
// 595 us, plus OFF_LPART placed in the pre-existing free gap between the end
// of NIDX (69632+32768=102400) and OFF_G (131072). No other offset moved.
// Mpart (16 x 1 MB split-K partials of F^T F) ALIASES the H region: consumed
// by buildG before matmulH writes H.
// ---------------------------------------------------------------------------
constexpr size_t OFF_ACC    = 0;         // 2 floats (legacy, still memset)
constexpr size_t OFF_S      = 1024;      // 512 f32 column sums
constexpr size_t OFF_BSTART = 3072;      // 101 ints: class bucket starts
constexpr size_t OFF_BIDX   = 4096;      // 8192 ints: rows grouped by class
constexpr size_t OFF_PIDX   = 36864;     // 8192 ints
constexpr size_t OFF_NIDX   = 69632;     // 8192 ints (ends 102400)
constexpr size_t OFF_LPART  = 102400;    // 2048 float2 loss partials (16 KB, ends 118784)
constexpr size_t OFF_G      = 131072;    // 512x512 f32 metric
constexpr size_t OFF_H      = 2097152;   // 8192x512 f32 = F*G (16 MB, ends 18874368)
constexpr size_t ZERO_BYTES = 3072;      // acc + S

// ---------------------------------------------------------------------------
// Kernel 1: column sums S[d] = sum_b F[b][d]  (unchanged from round 3)
// ---------------------------------------------------------------------------
__global__ __launch_bounds__(256) void colsum_kernel(const float* __restrict__ F,
                                                     float* __restrict__ S) {
  int b0 = blockIdx.x * 32;
  int t = threadIdx.x;
  float s0 = 0.f, s1 = 0.f;
  for (int r = 0; r < 32; ++r) {
    const float* row = F + (size_t)(b0 + r) * DIM;
    s0 += row[t];
    s1 += row[t + 256];
  }
  atomicAdd(&S[t], s0);
  atomicAdd(&S[t + 256], s1);
}

// ---------------------------------------------------------------------------
// Kernel 2: Mpart[z] = F[z-chunk]^T F[z-chunk], 128x64 tile, 8x4 frag, b128.
// grid (4, 8, 16), block 256.  (unchanged from round 3)
// ---------------------------------------------------------------------------
__global__ __launch_bounds__(256) void covmat_kernel(const float* __restrict__ F,
                                                     float* __restrict__ Mpart) {
  __shared__ float sA[32][132];
  __shared__ float sB[32][68];
  int i0 = blockIdx.x * 128;
  int j0 = blockIdx.y * 64;
  int k0 = blockIdx.z * 512;
  int tid = threadIdx.x;
  int ti = (tid >> 4) * 8;
  int tj = (tid & 15) * 4;
  float acc[8][4] = {};
  for (int kk = 0; kk < 512; kk += 32) {
#pragma unroll
    for (int r = 0; r < 4; ++r) {
      int idx = tid + 256 * r;
      int lr = idx >> 5, lc = (idx & 31) * 4;
      *(float4*)&sA[lr][lc] = *(const float4*)&F[(size_t)(k0 + kk + lr) * DIM + i0 + lc];
    }
#pragma unroll
    for (int r = 0; r < 2; ++r) {
      int idx = tid + 256 * r;
      int lr = idx >> 4, lc = (idx & 15) * 4;
      *(float4*)&sB[lr][lc] = *(const float4*)&F[(size_t)(k0 + kk + lr) * DIM + j0 + lc];
    }
    __syncthreads();
#pragma unroll
    for (int k = 0; k < 32; ++k) {
      float4 a0 = *(float4*)&sA[k][ti];
      float4 a1 = *(float4*)&sA[k][ti + 4];
      float4 b  = *(float4*)&sB[k][tj];
      float a[8] = {a0.x, a0.y, a0.z, a0.w, a1.x, a1.y, a1.z, a1.w};
      float bb[4] = {b.x, b.y, b.z, b.w};
#pragma unroll
      for (int x = 0; x < 8; ++x)
#pragma unroll
        for (int y = 0; y < 4; ++y) acc[x][y] += a[x] * bb[y];
    }
    __syncthreads();
  }
  float* out = Mpart + (size_t)blockIdx.z * DIM * DIM;
#pragma unroll
  for (int x = 0; x < 8; ++x) {
    float4 v = {acc[x][0], acc[x][1], acc[x][2], acc[x][3]};
    *(float4*)&out[(size_t)(i0 + ti + x) * DIM + j0 + tj] = v;
  }
}

// ---------------------------------------------------------------------------
// Kernel 3: G = (sum_z Mpart[z])/B - mean mean^T + I  (unchanged from round 3)
// ---------------------------------------------------------------------------
__global__ __launch_bounds__(256) void buildG_kernel(const float* __restrict__ Mpart,
                                                     const float* __restrict__ S,
                                                     float* __restrict__ G) {
  int idx = blockIdx.x * 256 + threadIdx.x;
  int i = idx >> 9, j = idx & 511;
  float m = 0.f;
#pragma unroll
  for (int z = 0; z < 16; ++z) m += Mpart[(size_t)z * DIM * DIM + idx];
  const float invB = 1.0f / (float)BSZ;
  float mi = S[i] * invB, mj = S[j] * invB;
  G[idx] = m * invB - mi * mj + (i == j ? 1.0f : 0.0f);
}

// ---------------------------------------------------------------------------
// Kernel 4: H = F * G. 128(m)x64(n) tile, 8x4 frag. grid (8, 64), block 256.
// (unchanged from round 3)
// ---------------------------------------------------------------------------
__global__ __launch_bounds__(256) void matmulH_kernel(const float* __restrict__ F,
                                                      const float* __restrict__ G,
                                                      float* __restrict__ H) {
  __shared__ float sF[128][36];
  __shared__ float sG[32][68];
  int n0 = blockIdx.x * 64;
  int m0 = blockIdx.y * 128;
  int tid = threadIdx.x;
  int tm = (tid >> 4) * 8;
  int tn = (tid & 15) * 4;
  float acc[8][4] = {};
  for (int k0 = 0; k0 < DIM; k0 += 32) {
#pragma unroll
    for (int r = 0; r < 4; ++r) {
      int idx = tid + 256 * r;
      int mm = idx >> 3, kk = (idx & 7) * 4;
      *(float4*)&sF[mm][kk] = *(const float4*)&F[(size_t)(m0 + mm) * DIM + k0 + kk];
    }
#pragma unroll
    for (int r = 0; r < 2; ++r) {
      int idx = tid + 256 * r;
      int lr = idx >> 4, lc = (idx & 15) * 4;
      *(float4*)&sG[lr][lc] = *(const float4*)&G[(size_t)(k0 + lr) * DIM + n0 + lc];
    }
    __syncthreads();
#pragma unroll
    for (int k4 = 0; k4 < 32; k4 += 4) {
      float4 a[8];
#pragma unroll
      for (int x = 0; x < 8; ++x) a[x] = *(float4*)&sF[tm + x][k4];
      float4 b[4];
#pragma unroll
      for (int j = 0; j < 4; ++j) b[j] = *(float4*)&sG[k4 + j][tn];
#pragma unroll
      for (int x = 0; x < 8; ++x) {
        float ax[4] = {a[x].x, a[x].y, a[x].z, a[x].w};
#pragma unroll
        for (int j = 0; j < 4; ++j) {
          float bj[4] = {b[j].x, b[j].y, b[j].z, b[j].w};
#pragma unroll
          for (int y = 0; y < 4; ++y) acc[x][y] += ax[j] * bj[y];
        }
      }
    }
    __syncthreads();
  }
#pragma unroll
  for (int x = 0; x < 8; ++x) {
    float4 v = {acc[x][0], acc[x][1], acc[x][2], acc[x][3]};
    *(float4*)&H[(size_t)(m0 + tm + x) * DIM + n0 + tn] = v;
  }
}

// ---------------------------------------------------------------------------
// Kernel 5: class buckets (single block).  (unchanged from round 3)
// ---------------------------------------------------------------------------
__global__ __launch_bounds__(256) void bucket_kernel(const int* __restrict__ labels,
                                                     int* __restrict__ bucketStart,
                                                     int* __restrict__ bucketIdx) {
  __shared__ int cnt[128];
  __shared__ int base[128];
  int tid = threadIdx.x;
  if (tid < 128) cnt[tid] = 0;
  __syncthreads();
  for (int b = tid; b < BSZ; b += 256) atomicAdd(&cnt[labels[b]], 1);
  __syncthreads();
  if (tid == 0) {
    int run = 0;
    for (int c = 0; c < 100; ++c) { base[c] = run; bucketStart[c] = run; run += cnt[c]; }
    bucketStart[100] = run;
  }
  __syncthreads();
  for (int b = tid; b < BSZ; b += 256) {
    int p = atomicAdd(&base[labels[b]], 1);
    bucketIdx[p] = b;
  }
}

// ---------------------------------------------------------------------------
// Kernel 6: negative argmax — uniform pass, one block per row.
// (unchanged from round 3: u64 running max in the loop)
// ---------------------------------------------------------------------------
__global__ __launch_bounds__(256) void negmax_kernel(const int* __restrict__ labels,
                                                     uint32_t kn0, uint32_t kn1,
                                                     int* __restrict__ negIdx) {
  __shared__ unsigned long long wmax[4];
  int i = blockIdx.x;
  int li = labels[i];
  uint32_t base = (uint32_t)(i << 13);
  unsigned long long best = 0;
  int c = threadIdx.x;
#pragma unroll 2
  for (int it = 0; it < 32; ++it, c += 256) {
    int lc = labels[c];
    uint32_t a0, a1;
    threefry2x32(kn0, kn1, 0u, base + (uint32_t)c, a0, a1);
    uint32_t bits = (a0 ^ a1) >> 9;
    unsigned long long comp = ((unsigned long long)bits << 32) | (uint32_t)(~c);
    if (lc == li) comp = 0;
    if (comp > best) best = comp;
  }
#pragma unroll
  for (int off = 32; off; off >>= 1) {
    unsigned long long o = __shfl_down(best, off);
    if (o > best) best = o;
  }
  int wid = threadIdx.x >> 6;
  if ((threadIdx.x & 63) == 0) wmax[wid] = best;
  __syncthreads();
  if (threadIdx.x == 0) {
    best = wmax[0];
    for (int w = 1; w < 4; ++w) if (wmax[w] > best) best = wmax[w];
    negIdx[i] = best ? (int)(~(uint32_t)best) : -1;
  }
}

// ---------------------------------------------------------------------------
// Kernel 7: positive argmax — bucketed, one wave per row.  (unchanged)
// ---------------------------------------------------------------------------
__global__ __launch_bounds__(256) void posmax_kernel(const int* __restrict__ labels,
                                                     const int* __restrict__ bucketStart,
                                                     const int* __restrict__ bucketIdx,
                                                     uint32_t kp0, uint32_t kp1,
                                                     int* __restrict__ posIdx) {
  int row = blockIdx.x * 4 + (threadIdx.x >> 6);
  int lane = threadIdx.x & 63;
  int cls = labels[row];
  int s = bucketStart[cls], e = bucketStart[cls + 1];
  uint32_t base = (uint32_t)(row << 13);
  unsigned long long best = 0;
  for (int t = s + lane; t < e; t += 64) {
    int cc = bucketIdx[t];
    uint32_t a0, a1;
    threefry2x32(kp0, kp1, 0u, base + (uint32_t)cc, a0, a1);
    uint32_t bits = (a0 ^ a1) >> 9;
    unsigned long long comp = ((unsigned long long)bits << 32) | (uint32_t)(~cc);
    if (cc == row) comp = 0;
    if (comp > best) best = comp;
  }
#pragma unroll
  for (int off = 32; off; off >>= 1) {
    unsigned long long o = __shfl_down(best, off);
    if (o > best) best = o;
  }
  if (lane == 0) posIdx[row] = best ? (int)(~(uint32_t)best) : -1;
}

// ---------------------------------------------------------------------------
// Kernel 8: per-row loss -> per-BLOCK partial. THE ONLY CHANGE vs the proven
// round-3 source: round-3 profile showed 16k same-address atomicAdds
// serializing (212 us, VALUBusy 1%). Now each block writes ONE float2 to a
// distinct address; no global atomics.
// ---------------------------------------------------------------------------
__global__ __launch_bounds__(256) void loss_kernel(const float* __restrict__ F,
                                                   const float* __restrict__ H,
                                                   const int* __restrict__ posIdx,
                                                   const int* __restrict__ negIdx,
                                                   float2* __restrict__ lossPart) {
  __shared__ float2 part[4];
  int row = blockIdx.x * 4 + (threadIdx.x >> 6);
  int lane = threadIdx.x & 63;
  int p = posIdx[row], n = negIdx[row];
  bool valid = (p >= 0) && (n >= 0);
  int ps = valid ? p : row;
  int ns = valid ? n : row;
  const float* Fi = F + (size_t)row * DIM;
  const float* Hi = H + (size_t)row * DIM;
  const float* Fp = F + (size_t)ps * DIM;
  const float* Hp = H + (size_t)ps * DIM;
  const float* Fn = F + (size_t)ns * DIM;
  const float* Hn = H + (size_t)ns * DIM;
  float qii = 0.f, qpp = 0.f, qip = 0.f, qnn = 0.f, qin = 0.f;
#pragma unroll
  for (int k = lane * 4; k < DIM; k += 256) {
    float4 fi = *(const float4*)&Fi[k], hi = *(const float4*)&Hi[k];
    float4 fp = *(const float4*)&Fp[k], hp = *(const float4*)&Hp[k];
    float4 fn = *(const float4*)&Fn[k], hn = *(const float4*)&Hn[k];
    qii += fi.x * hi.x + fi.y * hi.y + fi.z * hi.z + fi.w * hi.w;
    qpp += fp.x * hp.x + fp.y * hp.y + fp.z * hp.z + fp.w * hp.w;
    qip += fi.x * hp.x + fi.y * hp.y + fi.z * hp.z + fi.w * hp.w;
    qnn += fn.x * hn.x + fn.y * hn.y + fn.z * hn.z + fn.w * hn.w;
    qin += fi.x * hn.x + fi.y * hn.y + fi.z * hn.z + fi.w * hn.w;
  }
#pragma unroll
  for (int off = 32; off > 0; off >>= 1) {
    qii += __shfl_down(qii, off);
    qpp += __shfl_down(qpp, off);
    qip += __shfl_down(qip, off);
    qnn += __shfl_down(qnn, off);
    qin += __shfl_down(qin, off);
  }
  if (lane == 0) {
    float d2p = fmaxf(qii + qpp - 2.f * qip, 0.f);
    float d2n = fmaxf(qii + qnn - 2.f * qin, 0.f);
    float dpos = sqrtf(d2p + 1e-8f);
    float dneg = sqrtf(d2n + 1e-8f);
    float v = fmaxf(dpos - dneg + 1.0f, 0.0f);
    if (!valid) v = 0.f;
    part[threadIdx.x >> 6] = make_float2(v, valid ? 1.f : 0.f);
  }
  __syncthreads();
  if (threadIdx.x == 0) {
    float s = 0.f, c = 0.f;
#pragma unroll
    for (int w = 0; w < 4; ++w) { s += part[w].x; c += part[w].y; }
    lossPart[blockIdx.x] = make_float2(s, c);
  }
}

// ---------------------------------------------------------------------------
// Kernel 9: finalize — reduce 2048 block partials, single 256-thread block.
// ---------------------------------------------------------------------------
__global__ __launch_bounds__(256) void finalize_kernel(const float2* __restrict__ lossPart,
                                                       float* __restrict__ out) {
  __shared__ float2 wsum[4];
  int tid = threadIdx.x;
  float s = 0.f, c = 0.f;
  for (int z = tid; z < 2048; z += 256) {
    float2 v = lossPart[z];
    s += v.x; c += v.y;
  }
#pragma unroll
  for (int off = 32; off > 0; off >>= 1) {
    s += __shfl_down(s, off);
    c += __shfl_down(c, off);
  }
  if ((tid & 63) == 0) wsum[tid >> 6] = make_float2(s, c);
  __syncthreads();
  if (tid == 0) {
    s = 0.f; c = 0.f;
#pragma unroll
    for (int w = 0; w < 4; ++w) { s += wsum[w].x; c += wsum[w].y; }
    out[0] = s / fmaxf(c, 1.0f);
  }
}

// ---------------------------------------------------------------------------
extern "C" void kernel_launch(void* const* d_in, const int* in_sizes, int n_in,
                              void* d_out, int out_size, void* d_ws, size_t ws_size,
                              hipStream_t stream) {
  const float* F = (const float*)d_in[0];
  const int* labels = (const int*)d_in[1];
  float* out = (float*)d_out;
  char* ws = (char*)d_ws;

  float* S      = (float*)(ws + OFF_S);
  int* bStart   = (int*)(ws + OFF_BSTART);
  int* bIdx     = (int*)(ws + OFF_BIDX);
  int* posIdx   = (int*)(ws + OFF_PIDX);
  int* negIdx   = (int*)(ws + OFF_NIDX);
  float2* lPart = (float2*)(ws + OFF_LPART);
  float* G      = (float*)(ws + OFF_G);
  float* H      = (float*)(ws + OFF_H);
  float* Mpart  = H;   // 16 x 1MB split-K partials, consumed before H written

  // Partitionable (foldlike) split of jax.random.key(42):
  uint32_t kp0, kp1, kn0, kn1;
  threefry2x32(0u, 42u, 0u, 0u, kp0, kp1);
  threefry2x32(0u, 42u, 0u, 1u, kn0, kn1);

  hipMemsetAsync(ws, 0, ZERO_BYTES, stream);

  colsum_kernel<<<256, 256, 0, stream>>>(F, S);

  dim3 covGrid(4, 8, 16);
  covmat_kernel<<<covGrid, 256, 0, stream>>>(F, Mpart);

  buildG_kernel<<<(DIM * DIM) / 256, 256, 0, stream>>>(Mpart, S, G);

  bucket_kernel<<<1, 256, 0, stream>>>(labels, bStart, bIdx);

  negmax_kernel<<<BSZ, 256, 0, stream>>>(labels, kn0, kn1, negIdx);

  posmax_kernel<<<BSZ / 4, 256, 0, stream>>>(labels, bStart, bIdx, kp0, kp1, posIdx);

  dim3 hGrid(DIM / 64, BSZ / 128);
  matmulH_kernel<<<hGrid, 256, 0, stream>>>(F, G, H);

  loss_kernel<<<BSZ / 4, 256, 0, stream>>>(F, H, posIdx, negIdx, lPart);

  finalize_kernel<<<1, 256, 0, stream>>>(lPart, out);
}

// Round 9
// 405.223 us; speedup vs baseline: 1.9434x; 1.0153x over previous
//
#include <hip/hip_runtime.h>
#include <stdint.h>

// Problem constants (fixed by reference): B=8192 samples, D=512 dims, 100 classes.
#define BSZ   8192
#define DIM   512

// ---------------------------------------------------------------------------
// Threefry-2x32-20 (exact JAX semantics, partitionable mode: bits = y0 ^ y1).
// rotl compiles to v_alignbit_b32 (1 instr).
// ---------------------------------------------------------------------------
__host__ __device__ inline uint32_t rotl32(uint32_t v, int s) {
#if defined(__HIP_DEVICE_COMPILE__) && __has_builtin(__builtin_amdgcn_alignbit)
  return __builtin_amdgcn_alignbit(v, v, 32 - s);
#else
  return (v << s) | (v >> (32 - s));
#endif
}

__host__ __device__ inline void threefry2x32(uint32_t k0, uint32_t k1,
                                             uint32_t x0, uint32_t x1,
                                             uint32_t& o0, uint32_t& o1) {
  uint32_t ks2 = k0 ^ k1 ^ 0x1BD11BDAu;
  x0 += k0; x1 += k1;
  x0 += x1; x1 = rotl32(x1, 13); x1 ^= x0;
  x0 += x1; x1 = rotl32(x1, 15); x1 ^= x0;
  x0 += x1; x1 = rotl32(x1, 26); x1 ^= x0;
  x0 += x1; x1 = rotl32(x1,  6); x1 ^= x0;
  x0 += k1; x1 += ks2 + 1u;
  x0 += x1; x1 = rotl32(x1, 17); x1 ^= x0;
  x0 += x1; x1 = rotl32(x1, 29); x1 ^= x0;
  x0 += x1; x1 = rotl32(x1, 16); x1 ^= x0;
  x0 += x1; x1 = rotl32(x1, 24); x1 ^= x0;
  x0 += ks2; x1 += k0 + 2u;
  x0 += x1; x1 = rotl32(x1, 13); x1 ^= x0;
  x0 += x1; x1 = rotl32(x1, 15); x1 ^= x0;
  x0 += x1; x1 = rotl32(x1, 26); x1 ^= x0;
  x0 += x1; x1 = rotl32(x1,  6); x1 ^= x0;
  x0 += k0; x1 += k1 + 3u;
  x0 += x1; x1 = rotl32(x1, 17); x1 ^= x0;
  x0 += x1; x1 = rotl32(x1, 29); x1 ^= x0;
  x0 += x1; x1 = rotl32(x1, 16); x1 ^= x0;
  x0 += x1; x1 = rotl32(x1, 24); x1 ^= x0;
  x0 += k1; x1 += ks2 + 4u;
  x0 += x1; x1 = rotl32(x1, 13); x1 ^= x0;
  x0 += x1; x1 = rotl32(x1, 15); x1 ^= x0;
  x0 += x1; x1 = rotl32(x1, 26); x1 ^= x0;
  x0 += x1; x1 = rotl32(x1,  6); x1 ^= x0;
  x0 += ks2; x1 += k0 + 5u;
  o0 = x0; o1 = x1;
}

// ---------------------------------------------------------------------------
// Workspace layout (bytes) — byte-identical to the round-7 source that
// benched at 411 us. Mpart (16 x 1 MB split-K partials of F^T F) ALIASES the
// H region: consumed by buildG before matmulH writes H.
// ---------------------------------------------------------------------------
constexpr size_t OFF_ACC    = 0;         // 2 floats (legacy, still memset)
constexpr size_t OFF_S      = 1024;      // 512 f32 column sums
constexpr size_t OFF_BSTART = 3072;      // 101 ints: class bucket starts
constexpr size_t OFF_BIDX   = 4096;      // 8192 ints: rows grouped by class
constexpr size_t OFF_PIDX   = 36864;     // 8192 ints
constexpr size_t OFF_NIDX   = 69632;     // 8192 ints (ends 102400)
constexpr size_t OFF_LPART  = 102400;    // 2048 float2 loss partials (ends 118784)
constexpr size_t OFF_G      = 131072;    // 512x512 f32 metric
constexpr size_t OFF_H      = 2097152;   // 8192x512 f32 = F*G (16 MB, ends 18874368)
constexpr size_t ZERO_BYTES = 3072;      // acc + S

// ---------------------------------------------------------------------------
// Kernel 1: column sums S[d] = sum_b F[b][d]  (unchanged, proven)
// ---------------------------------------------------------------------------
__global__ __launch_bounds__(256) void colsum_kernel(const float* __restrict__ F,
                                                     float* __restrict__ S) {
  int b0 = blockIdx.x * 32;
  int t = threadIdx.x;
  float s0 = 0.f, s1 = 0.f;
  for (int r = 0; r < 32; ++r) {
    const float* row = F + (size_t)(b0 + r) * DIM;
    s0 += row[t];
    s1 += row[t + 256];
  }
  atomicAdd(&S[t], s0);
  atomicAdd(&S[t + 256], s1);
}

// ---------------------------------------------------------------------------
// Kernel 2: Mpart[z] = F[z-chunk]^T F[z-chunk], 128x64 tile, 8x4 frag, b128.
// grid (4, 8, 16), block 256.  (unchanged, proven)
// ---------------------------------------------------------------------------
__global__ __launch_bounds__(256) void covmat_kernel(const float* __restrict__ F,
                                                     float* __restrict__ Mpart) {
  __shared__ float sA[32][132];
  __shared__ float sB[32][68];
  int i0 = blockIdx.x * 128;
  int j0 = blockIdx.y * 64;
  int k0 = blockIdx.z * 512;
  int tid = threadIdx.x;
  int ti = (tid >> 4) * 8;
  int tj = (tid & 15) * 4;
  float acc[8][4] = {};
  for (int kk = 0; kk < 512; kk += 32) {
#pragma unroll
    for (int r = 0; r < 4; ++r) {
      int idx = tid + 256 * r;
      int lr = idx >> 5, lc = (idx & 31) * 4;
      *(float4*)&sA[lr][lc] = *(const float4*)&F[(size_t)(k0 + kk + lr) * DIM + i0 + lc];
    }
#pragma unroll
    for (int r = 0; r < 2; ++r) {
      int idx = tid + 256 * r;
      int lr = idx >> 4, lc = (idx & 15) * 4;
      *(float4*)&sB[lr][lc] = *(const float4*)&F[(size_t)(k0 + kk + lr) * DIM + j0 + lc];
    }
    __syncthreads();
#pragma unroll
    for (int k = 0; k < 32; ++k) {
      float4 a0 = *(float4*)&sA[k][ti];
      float4 a1 = *(float4*)&sA[k][ti + 4];
      float4 b  = *(float4*)&sB[k][tj];
      float a[8] = {a0.x, a0.y, a0.z, a0.w, a1.x, a1.y, a1.z, a1.w};
      float bb[4] = {b.x, b.y, b.z, b.w};
#pragma unroll
      for (int x = 0; x < 8; ++x)
#pragma unroll
        for (int y = 0; y < 4; ++y) acc[x][y] += a[x] * bb[y];
    }
    __syncthreads();
  }
  float* out = Mpart + (size_t)blockIdx.z * DIM * DIM;
#pragma unroll
  for (int x = 0; x < 8; ++x) {
    float4 v = {acc[x][0], acc[x][1], acc[x][2], acc[x][3]};
    *(float4*)&out[(size_t)(i0 + ti + x) * DIM + j0 + tj] = v;
  }
}

// ---------------------------------------------------------------------------
// Kernel 3: G = (sum_z Mpart[z])/B - mean mean^T + I  (unchanged, proven)
// ---------------------------------------------------------------------------
__global__ __launch_bounds__(256) void buildG_kernel(const float* __restrict__ Mpart,
                                                     const float* __restrict__ S,
                                                     float* __restrict__ G) {
  int idx = blockIdx.x * 256 + threadIdx.x;
  int i = idx >> 9, j = idx & 511;
  float m = 0.f;
#pragma unroll
  for (int z = 0; z < 16; ++z) m += Mpart[(size_t)z * DIM * DIM + idx];
  const float invB = 1.0f / (float)BSZ;
  float mi = S[i] * invB, mj = S[j] * invB;
  G[idx] = m * invB - mi * mj + (i == j ? 1.0f : 0.0f);
}

// ---------------------------------------------------------------------------
// Kernel 4: H = F * G. 128(m)x64(n) tile, 8x4 frag. grid (8, 64), block 256.
// (unchanged, proven)
// ---------------------------------------------------------------------------
__global__ __launch_bounds__(256) void matmulH_kernel(const float* __restrict__ F,
                                                      const float* __restrict__ G,
                                                      float* __restrict__ H) {
  __shared__ float sF[128][36];
  __shared__ float sG[32][68];
  int n0 = blockIdx.x * 64;
  int m0 = blockIdx.y * 128;
  int tid = threadIdx.x;
  int tm = (tid >> 4) * 8;
  int tn = (tid & 15) * 4;
  float acc[8][4] = {};
  for (int k0 = 0; k0 < DIM; k0 += 32) {
#pragma unroll
    for (int r = 0; r < 4; ++r) {
      int idx = tid + 256 * r;
      int mm = idx >> 3, kk = (idx & 7) * 4;
      *(float4*)&sF[mm][kk] = *(const float4*)&F[(size_t)(m0 + mm) * DIM + k0 + kk];
    }
#pragma unroll
    for (int r = 0; r < 2; ++r) {
      int idx = tid + 256 * r;
      int lr = idx >> 4, lc = (idx & 15) * 4;
      *(float4*)&sG[lr][lc] = *(const float4*)&G[(size_t)(k0 + lr) * DIM + n0 + lc];
    }
    __syncthreads();
#pragma unroll
    for (int k4 = 0; k4 < 32; k4 += 4) {
      float4 a[8];
#pragma unroll
      for (int x = 0; x < 8; ++x) a[x] = *(float4*)&sF[tm + x][k4];
      float4 b[4];
#pragma unroll
      for (int j = 0; j < 4; ++j) b[j] = *(float4*)&sG[k4 + j][tn];
#pragma unroll
      for (int x = 0; x < 8; ++x) {
        float ax[4] = {a[x].x, a[x].y, a[x].z, a[x].w};
#pragma unroll
        for (int j = 0; j < 4; ++j) {
          float bj[4] = {b[j].x, b[j].y, b[j].z, b[j].w};
#pragma unroll
          for (int y = 0; y < 4; ++y) acc[x][y] += ax[j] * bj[y];
        }
      }
    }
    __syncthreads();
  }
#pragma unroll
  for (int x = 0; x < 8; ++x) {
    float4 v = {acc[x][0], acc[x][1], acc[x][2], acc[x][3]};
    *(float4*)&H[(size_t)(m0 + tm + x) * DIM + n0 + tn] = v;
  }
}

// ---------------------------------------------------------------------------
// Kernel 5: class buckets (single block).  (unchanged, proven — r7 signature)
// ---------------------------------------------------------------------------
__global__ __launch_bounds__(256) void bucket_kernel(const int* __restrict__ labels,
                                                     int* __restrict__ bucketStart,
                                                     int* __restrict__ bucketIdx) {
  __shared__ int cnt[128];
  __shared__ int base[128];
  int tid = threadIdx.x;
  if (tid < 128) cnt[tid] = 0;
  __syncthreads();
  for (int b = tid; b < BSZ; b += 256) atomicAdd(&cnt[labels[b]], 1);
  __syncthreads();
  if (tid == 0) {
    int run = 0;
    for (int c = 0; c < 100; ++c) { base[c] = run; bucketStart[c] = run; run += cnt[c]; }
    bucketStart[100] = run;
  }
  __syncthreads();
  for (int b = tid; b < BSZ; b += 256) {
    int p = atomicAdd(&base[labels[b]], 1);
    bucketIdx[p] = b;
  }
}

// ---------------------------------------------------------------------------
// Kernel 6: negative argmax — proven u64-max loop (r7), with the ONLY change
// being the label source: labels staged once into an 8 KB LDS u8 array
// (packed 4:1 from int4 loads), replacing the per-iteration global load +
// 64-bit addressing + vmcnt stall in the hot loop. The 67.1M-hash loop body
// itself is byte-identical to the 411-us r7 binary.
// NOTE: the packed-32 comp variant (r4/r5/r6/r8) trio-failed 4/4 — retired.
// ---------------------------------------------------------------------------
__global__ __launch_bounds__(256) void negmax_kernel(const int* __restrict__ labels,
                                                     uint32_t kn0, uint32_t kn1,
                                                     int* __restrict__ negIdx) {
  __shared__ __align__(16) uint8_t slab[BSZ];
  __shared__ unsigned long long wmax[4];
  int tid = threadIdx.x;
  // stage labels -> u8 LDS: 8 passes x 1024 labels (each thread packs int4 -> u32)
  {
    uint32_t* s32 = (uint32_t*)slab;
#pragma unroll
    for (int pass = 0; pass < 8; ++pass) {
      int idx = pass * 1024 + tid * 4;
      int4 l4 = *(const int4*)&labels[idx];
      uint32_t packed = (uint32_t)(l4.x & 0xFF) | ((uint32_t)(l4.y & 0xFF) << 8) |
                        ((uint32_t)(l4.z & 0xFF) << 16) | ((uint32_t)(l4.w & 0xFF) << 24);
      s32[pass * 256 + tid] = packed;
    }
  }
  __syncthreads();
  int i = blockIdx.x;
  uint32_t li = slab[i];                 // same byte for all lanes -> broadcast
  uint32_t base = (uint32_t)(i << 13);
  unsigned long long best = 0;
  int c = tid;
#pragma unroll 2
  for (int it = 0; it < 32; ++it, c += 256) {
    uint32_t lc = slab[c];               // consecutive bytes: 4 lanes/dword, broadcast
    uint32_t a0, a1;
    threefry2x32(kn0, kn1, 0u, base + (uint32_t)c, a0, a1);
    uint32_t bits = (a0 ^ a1) >> 9;
    unsigned long long comp = ((unsigned long long)bits << 32) | (uint32_t)(~c);
    if (lc == li) comp = 0;
    if (comp > best) best = comp;
  }
#pragma unroll
  for (int off = 32; off; off >>= 1) {
    unsigned long long o = __shfl_down(best, off);
    if (o > best) best = o;
  }
  int wid = tid >> 6;
  if ((tid & 63) == 0) wmax[wid] = best;
  __syncthreads();
  if (tid == 0) {
    best = wmax[0];
    for (int w = 1; w < 4; ++w) if (wmax[w] > best) best = wmax[w];
    negIdx[i] = best ? (int)(~(uint32_t)best) : -1;
  }
}

// ---------------------------------------------------------------------------
// Kernel 7: positive argmax — bucketed, one wave per row.  (unchanged, proven)
// ---------------------------------------------------------------------------
__global__ __launch_bounds__(256) void posmax_kernel(const int* __restrict__ labels,
                                                     const int* __restrict__ bucketStart,
                                                     const int* __restrict__ bucketIdx,
                                                     uint32_t kp0, uint32_t kp1,
                                                     int* __restrict__ posIdx) {
  int row = blockIdx.x * 4 + (threadIdx.x >> 6);
  int lane = threadIdx.x & 63;
  int cls = labels[row];
  int s = bucketStart[cls], e = bucketStart[cls + 1];
  uint32_t base = (uint32_t)(row << 13);
  unsigned long long best = 0;
  for (int t = s + lane; t < e; t += 64) {
    int cc = bucketIdx[t];
    uint32_t a0, a1;
    threefry2x32(kp0, kp1, 0u, base + (uint32_t)cc, a0, a1);
    uint32_t bits = (a0 ^ a1) >> 9;
    unsigned long long comp = ((unsigned long long)bits << 32) | (uint32_t)(~cc);
    if (cc == row) comp = 0;
    if (comp > best) best = comp;
  }
#pragma unroll
  for (int off = 32; off; off >>= 1) {
    unsigned long long o = __shfl_down(best, off);
    if (o > best) best = o;
  }
  if (lane == 0) posIdx[row] = best ? (int)(~(uint32_t)best) : -1;
}

// ---------------------------------------------------------------------------
// Kernel 8: per-row loss -> per-BLOCK partial (no global atomics; proven).
// ---------------------------------------------------------------------------
__global__ __launch_bounds__(256) void loss_kernel(const float* __restrict__ F,
                                                   const float* __restrict__ H,
                                                   const int* __restrict__ posIdx,
                                                   const int* __restrict__ negIdx,
                                                   float2* __restrict__ lossPart) {
  __shared__ float2 part[4];
  int row = blockIdx.x * 4 + (threadIdx.x >> 6);
  int lane = threadIdx.x & 63;
  int p = posIdx[row], n = negIdx[row];
  bool valid = (p >= 0) && (n >= 0);
  int ps = valid ? p : row;
  int ns = valid ? n : row;
  const float* Fi = F + (size_t)row * DIM;
  const float* Hi = H + (size_t)row * DIM;
  const float* Fp = F + (size_t)ps * DIM;
  const float* Hp = H + (size_t)ps * DIM;
  const float* Fn = F + (size_t)ns * DIM;
  const float* Hn = H + (size_t)ns * DIM;
  float qii = 0.f, qpp = 0.f, qip = 0.f, qnn = 0.f, qin = 0.f;
#pragma unroll
  for (int k = lane * 4; k < DIM; k += 256) {
    float4 fi = *(const float4*)&Fi[k], hi = *(const float4*)&Hi[k];
    float4 fp = *(const float4*)&Fp[k], hp = *(const float4*)&Hp[k];
    float4 fn = *(const float4*)&Fn[k], hn = *(const float4*)&Hn[k];
    qii += fi.x * hi.x + fi.y * hi.y + fi.z * hi.z + fi.w * hi.w;
    qpp += fp.x * hp.x + fp.y * hp.y + fp.z * hp.z + fp.w * hp.w;
    qip += fi.x * hp.x + fi.y * hp.y + fi.z * hp.z + fi.w * hp.w;
    qnn += fn.x * hn.x + fn.y * hn.y + fn.z * hn.z + fn.w * hn.w;
    qin += fi.x * hn.x + fi.y * hn.y + fi.z * hn.z + fi.w * hn.w;
  }
#pragma unroll
  for (int off = 32; off > 0; off >>= 1) {
    qii += __shfl_down(qii, off);
    qpp += __shfl_down(qpp, off);
    qip += __shfl_down(qip, off);
    qnn += __shfl_down(qnn, off);
    qin += __shfl_down(qin, off);
  }
  if (lane == 0) {
    float d2p = fmaxf(qii + qpp - 2.f * qip, 0.f);
    float d2n = fmaxf(qii + qnn - 2.f * qin, 0.f);
    float dpos = sqrtf(d2p + 1e-8f);
    float dneg = sqrtf(d2n + 1e-8f);
    float v = fmaxf(dpos - dneg + 1.0f, 0.0f);
    if (!valid) v = 0.f;
    part[threadIdx.x >> 6] = make_float2(v, valid ? 1.f : 0.f);
  }
  __syncthreads();
  if (threadIdx.x == 0) {
    float s = 0.f, c = 0.f;
#pragma unroll
    for (int w = 0; w < 4; ++w) { s += part[w].x; c += part[w].y; }
    lossPart[blockIdx.x] = make_float2(s, c);
  }
}

// ---------------------------------------------------------------------------
// Kernel 9: finalize — reduce 2048 block partials, single 256-thread block.
// ---------------------------------------------------------------------------
__global__ __launch_bounds__(256) void finalize_kernel(const float2* __restrict__ lossPart,
                                                       float* __restrict__ out) {
  __shared__ float2 wsum[4];
  int tid = threadIdx.x;
  float s = 0.f, c = 0.f;
  for (int z = tid; z < 2048; z += 256) {
    float2 v = lossPart[z];
    s += v.x; c += v.y;
  }
#pragma unroll
  for (int off = 32; off > 0; off >>= 1) {
    s += __shfl_down(s, off);
    c += __shfl_down(c, off);
  }
  if ((tid & 63) == 0) wsum[tid >> 6] = make_float2(s, c);
  __syncthreads();
  if (tid == 0) {
    s = 0.f; c = 0.f;
#pragma unroll
    for (int w = 0; w < 4; ++w) { s += wsum[w].x; c += wsum[w].y; }
    out[0] = s / fmaxf(c, 1.0f);
  }
}

// ---------------------------------------------------------------------------
extern "C" void kernel_launch(void* const* d_in, const int* in_sizes, int n_in,
                              void* d_out, int out_size, void* d_ws, size_t ws_size,
                              hipStream_t stream) {
  const float* F = (const float*)d_in[0];
  const int* labels = (const int*)d_in[1];
  float* out = (float*)d_out;
  char* ws = (char*)d_ws;

  float* S      = (float*)(ws + OFF_S);
  int* bStart   = (int*)(ws + OFF_BSTART);
  int* bIdx     = (int*)(ws + OFF_BIDX);
  int* posIdx   = (int*)(ws + OFF_PIDX);
  int* negIdx   = (int*)(ws + OFF_NIDX);
  float2* lPart = (float2*)(ws + OFF_LPART);
  float* G      = (float*)(ws + OFF_G);
  float* H      = (float*)(ws + OFF_H);
  float* Mpart  = H;   // 16 x 1MB split-K partials, consumed before H written

  // Partitionable (foldlike) split of jax.random.key(42):
  uint32_t kp0, kp1, kn0, kn1;
  threefry2x32(0u, 42u, 0u, 0u, kp0, kp1);
  threefry2x32(0u, 42u, 0u, 1u, kn0, kn1);

  hipMemsetAsync(ws, 0, ZERO_BYTES, stream);

  colsum_kernel<<<256, 256, 0, stream>>>(F, S);

  dim3 covGrid(4, 8, 16);
  covmat_kernel<<<covGrid, 256, 0, stream>>>(F, Mpart);

  buildG_kernel<<<(DIM * DIM) / 256, 256, 0, stream>>>(Mpart, S, G);

  bucket_kernel<<<1, 256, 0, stream>>>(labels, bStart, bIdx);

  negmax_kernel<<<BSZ, 256, 0, stream>>>(labels, kn0, kn1, negIdx);

  posmax_kernel<<<BSZ / 4, 256, 0, stream>>>(labels, bStart, bIdx, kp0, kp1, posIdx);

  dim3 hGrid(DIM / 64, BSZ / 128);
  matmulH_kernel<<<hGrid, 256, 0, stream>>>(F, G, H);

  loss_kernel<<<BSZ / 4, 256, 0, stream>>>(F, H, posIdx, negIdx, lPart);

  finalize_kernel<<<1, 256, 0, stream>>>(lPart, out);
}

// Round 10
// 399.394 us; speedup vs baseline: 1.9718x; 1.0146x over previous
//
#include <hip/hip_runtime.h>
#include <stdint.h>

// Problem constants (fixed by reference): B=8192 samples, D=512 dims, 100 classes.
#define BSZ   8192
#define DIM   512

// ---------------------------------------------------------------------------
// Threefry-2x32-20 (exact JAX semantics, partitionable mode: bits = y0 ^ y1).
// The rotate idiom is pattern-matched by LLVM to v_alignbit_b32.
// ---------------------------------------------------------------------------
__host__ __device__ inline uint32_t rotl32(uint32_t v, int s) {
#if defined(__HIP_DEVICE_COMPILE__) && __has_builtin(__builtin_amdgcn_alignbit)
  return __builtin_amdgcn_alignbit(v, v, 32 - s);
#else
  return (v << s) | (v >> (32 - s));
#endif
}

__host__ __device__ inline void threefry2x32(uint32_t k0, uint32_t k1,
                                             uint32_t x0, uint32_t x1,
                                             uint32_t& o0, uint32_t& o1) {
  uint32_t ks2 = k0 ^ k1 ^ 0x1BD11BDAu;
  x0 += k0; x1 += k1;
  x0 += x1; x1 = rotl32(x1, 13); x1 ^= x0;
  x0 += x1; x1 = rotl32(x1, 15); x1 ^= x0;
  x0 += x1; x1 = rotl32(x1, 26); x1 ^= x0;
  x0 += x1; x1 = rotl32(x1,  6); x1 ^= x0;
  x0 += k1; x1 += ks2 + 1u;
  x0 += x1; x1 = rotl32(x1, 17); x1 ^= x0;
  x0 += x1; x1 = rotl32(x1, 29); x1 ^= x0;
  x0 += x1; x1 = rotl32(x1, 16); x1 ^= x0;
  x0 += x1; x1 = rotl32(x1, 24); x1 ^= x0;
  x0 += ks2; x1 += k0 + 2u;
  x0 += x1; x1 = rotl32(x1, 13); x1 ^= x0;
  x0 += x1; x1 = rotl32(x1, 15); x1 ^= x0;
  x0 += x1; x1 = rotl32(x1, 26); x1 ^= x0;
  x0 += x1; x1 = rotl32(x1,  6); x1 ^= x0;
  x0 += k0; x1 += k1 + 3u;
  x0 += x1; x1 = rotl32(x1, 17); x1 ^= x0;
  x0 += x1; x1 = rotl32(x1, 29); x1 ^= x0;
  x0 += x1; x1 = rotl32(x1, 16); x1 ^= x0;
  x0 += x1; x1 = rotl32(x1, 24); x1 ^= x0;
  x0 += k1; x1 += ks2 + 4u;
  x0 += x1; x1 = rotl32(x1, 13); x1 ^= x0;
  x0 += x1; x1 = rotl32(x1, 15); x1 ^= x0;
  x0 += x1; x1 = rotl32(x1, 26); x1 ^= x0;
  x0 += x1; x1 = rotl32(x1,  6); x1 ^= x0;
  x0 += ks2; x1 += k0 + 5u;
  o0 = x0; o1 = x1;
}

// ---------------------------------------------------------------------------
// Workspace layout (bytes) — byte-identical to the passing r7/r9 sources.
// Mpart (16 x 1 MB split-K partials of F^T F) ALIASES the H region: consumed
// by buildG before matmulH writes H.
// ---------------------------------------------------------------------------
constexpr size_t OFF_ACC    = 0;         // 2 floats (legacy, still memset)
constexpr size_t OFF_S      = 1024;      // 512 f32 column sums
constexpr size_t OFF_BSTART = 3072;      // 101 ints: class bucket starts
constexpr size_t OFF_BIDX   = 4096;      // 8192 ints: rows grouped by class
constexpr size_t OFF_PIDX   = 36864;     // 8192 ints
constexpr size_t OFF_NIDX   = 69632;     // 8192 ints (ends 102400)
constexpr size_t OFF_LPART  = 102400;    // 2048 float2 loss partials (ends 118784)
constexpr size_t OFF_G      = 131072;    // 512x512 f32 metric
constexpr size_t OFF_H      = 2097152;   // 8192x512 f32 = F*G (16 MB, ends 18874368)
constexpr size_t ZERO_BYTES = 3072;      // acc + S

// ---------------------------------------------------------------------------
// Kernel 1: column sums S[d] = sum_b F[b][d]  (unchanged, proven)
// ---------------------------------------------------------------------------
__global__ __launch_bounds__(256) void colsum_kernel(const float* __restrict__ F,
                                                     float* __restrict__ S) {
  int b0 = blockIdx.x * 32;
  int t = threadIdx.x;
  float s0 = 0.f, s1 = 0.f;
  for (int r = 0; r < 32; ++r) {
    const float* row = F + (size_t)(b0 + r) * DIM;
    s0 += row[t];
    s1 += row[t + 256];
  }
  atomicAdd(&S[t], s0);
  atomicAdd(&S[t + 256], s1);
}

// ---------------------------------------------------------------------------
// Kernel 2: Mpart[z] = F[z-chunk]^T F[z-chunk], 128x64 tile, 8x4 frag, b128.
// grid (4, 8, 16), block 256.  (unchanged, proven)
// ---------------------------------------------------------------------------
__global__ __launch_bounds__(256) void covmat_kernel(const float* __restrict__ F,
                                                     float* __restrict__ Mpart) {
  __shared__ float sA[32][132];
  __shared__ float sB[32][68];
  int i0 = blockIdx.x * 128;
  int j0 = blockIdx.y * 64;
  int k0 = blockIdx.z * 512;
  int tid = threadIdx.x;
  int ti = (tid >> 4) * 8;
  int tj = (tid & 15) * 4;
  float acc[8][4] = {};
  for (int kk = 0; kk < 512; kk += 32) {
#pragma unroll
    for (int r = 0; r < 4; ++r) {
      int idx = tid + 256 * r;
      int lr = idx >> 5, lc = (idx & 31) * 4;
      *(float4*)&sA[lr][lc] = *(const float4*)&F[(size_t)(k0 + kk + lr) * DIM + i0 + lc];
    }
#pragma unroll
    for (int r = 0; r < 2; ++r) {
      int idx = tid + 256 * r;
      int lr = idx >> 4, lc = (idx & 15) * 4;
      *(float4*)&sB[lr][lc] = *(const float4*)&F[(size_t)(k0 + kk + lr) * DIM + j0 + lc];
    }
    __syncthreads();
#pragma unroll
    for (int k = 0; k < 32; ++k) {
      float4 a0 = *(float4*)&sA[k][ti];
      float4 a1 = *(float4*)&sA[k][ti + 4];
      float4 b  = *(float4*)&sB[k][tj];
      float a[8] = {a0.x, a0.y, a0.z, a0.w, a1.x, a1.y, a1.z, a1.w};
      float bb[4] = {b.x, b.y, b.z, b.w};
#pragma unroll
      for (int x = 0; x < 8; ++x)
#pragma unroll
        for (int y = 0; y < 4; ++y) acc[x][y] += a[x] * bb[y];
    }
    __syncthreads();
  }
  float* out = Mpart + (size_t)blockIdx.z * DIM * DIM;
#pragma unroll
  for (int x = 0; x < 8; ++x) {
    float4 v = {acc[x][0], acc[x][1], acc[x][2], acc[x][3]};
    *(float4*)&out[(size_t)(i0 + ti + x) * DIM + j0 + tj] = v;
  }
}

// ---------------------------------------------------------------------------
// Kernel 3: G = (sum_z Mpart[z])/B - mean mean^T + I  (unchanged, proven)
// ---------------------------------------------------------------------------
__global__ __launch_bounds__(256) void buildG_kernel(const float* __restrict__ Mpart,
                                                     const float* __restrict__ S,
                                                     float* __restrict__ G) {
  int idx = blockIdx.x * 256 + threadIdx.x;
  int i = idx >> 9, j = idx & 511;
  float m = 0.f;
#pragma unroll
  for (int z = 0; z < 16; ++z) m += Mpart[(size_t)z * DIM * DIM + idx];
  const float invB = 1.0f / (float)BSZ;
  float mi = S[i] * invB, mj = S[j] * invB;
  G[idx] = m * invB - mi * mj + (i == j ? 1.0f : 0.0f);
}

// ---------------------------------------------------------------------------
// Kernel 4: H = F * G. 128(m)x64(n) tile, 8x4 frag. grid (8, 64), block 256.
// (unchanged, proven)
// ---------------------------------------------------------------------------
__global__ __launch_bounds__(256) void matmulH_kernel(const float* __restrict__ F,
                                                      const float* __restrict__ G,
                                                      float* __restrict__ H) {
  __shared__ float sF[128][36];
  __shared__ float sG[32][68];
  int n0 = blockIdx.x * 64;
  int m0 = blockIdx.y * 128;
  int tid = threadIdx.x;
  int tm = (tid >> 4) * 8;
  int tn = (tid & 15) * 4;
  float acc[8][4] = {};
  for (int k0 = 0; k0 < DIM; k0 += 32) {
#pragma unroll
    for (int r = 0; r < 4; ++r) {
      int idx = tid + 256 * r;
      int mm = idx >> 3, kk = (idx & 7) * 4;
      *(float4*)&sF[mm][kk] = *(const float4*)&F[(size_t)(m0 + mm) * DIM + k0 + kk];
    }
#pragma unroll
    for (int r = 0; r < 2; ++r) {
      int idx = tid + 256 * r;
      int lr = idx >> 4, lc = (idx & 15) * 4;
      *(float4*)&sG[lr][lc] = *(const float4*)&G[(size_t)(k0 + lr) * DIM + n0 + lc];
    }
    __syncthreads();
#pragma unroll
    for (int k4 = 0; k4 < 32; k4 += 4) {
      float4 a[8];
#pragma unroll
      for (int x = 0; x < 8; ++x) a[x] = *(float4*)&sF[tm + x][k4];
      float4 b[4];
#pragma unroll
      for (int j = 0; j < 4; ++j) b[j] = *(float4*)&sG[k4 + j][tn];
#pragma unroll
      for (int x = 0; x < 8; ++x) {
        float ax[4] = {a[x].x, a[x].y, a[x].z, a[x].w};
#pragma unroll
        for (int j = 0; j < 4; ++j) {
          float bj[4] = {b[j].x, b[j].y, b[j].z, b[j].w};
#pragma unroll
          for (int y = 0; y < 4; ++y) acc[x][y] += ax[j] * bj[y];
        }
      }
    }
    __syncthreads();
  }
#pragma unroll
  for (int x = 0; x < 8; ++x) {
    float4 v = {acc[x][0], acc[x][1], acc[x][2], acc[x][3]};
    *(float4*)&H[(size_t)(m0 + tm + x) * DIM + n0 + tn] = v;
  }
}

// ---------------------------------------------------------------------------
// Kernel 5: class buckets (single block).  (unchanged, proven)
// ---------------------------------------------------------------------------
__global__ __launch_bounds__(256) void bucket_kernel(const int* __restrict__ labels,
                                                     int* __restrict__ bucketStart,
                                                     int* __restrict__ bucketIdx) {
  __shared__ int cnt[128];
  __shared__ int base[128];
  int tid = threadIdx.x;
  if (tid < 128) cnt[tid] = 0;
  __syncthreads();
  for (int b = tid; b < BSZ; b += 256) atomicAdd(&cnt[labels[b]], 1);
  __syncthreads();
  if (tid == 0) {
    int run = 0;
    for (int c = 0; c < 100; ++c) { base[c] = run; bucketStart[c] = run; run += cnt[c]; }
    bucketStart[100] = run;
  }
  __syncthreads();
  for (int b = tid; b < BSZ; b += 256) {
    int p = atomicAdd(&base[labels[b]], 1);
    bucketIdx[p] = b;
  }
}

// ---------------------------------------------------------------------------
// Kernel 6: negative argmax — r9's proven u64-max tail, restructured for ILP:
// each lane runs FOUR independent hash chains (columns c, c+256, c+512,
// c+768) into four separate u64 accumulators, merged after the loop. Max over
// disjoint partitions is order-independent and each composite embeds ~c, so
// the result is bit-identical to the r7/r9 single-chain loop. This tests the
// latency-bound hypothesis (serial threefry chain, ~4cy dependent latency):
// if correct, the wave no longer relies on TLP alone to cover the chain.
// NOTE: packed-32 comp variant (r4/5/6/8) trio-failed 4/4 — retired.
// ---------------------------------------------------------------------------
__global__ __launch_bounds__(256) void negmax_kernel(const int* __restrict__ labels,
                                                     uint32_t kn0, uint32_t kn1,
                                                     int* __restrict__ negIdx) {
  __shared__ __align__(16) uint8_t slab[BSZ];
  __shared__ unsigned long long wmax[4];
  int tid = threadIdx.x;
  // stage labels -> u8 LDS: 8 passes x 1024 labels (each thread packs int4 -> u32)
  {
    uint32_t* s32 = (uint32_t*)slab;
#pragma unroll
    for (int pass = 0; pass < 8; ++pass) {
      int idx = pass * 1024 + tid * 4;
      int4 l4 = *(const int4*)&labels[idx];
      uint32_t packed = (uint32_t)(l4.x & 0xFF) | ((uint32_t)(l4.y & 0xFF) << 8) |
                        ((uint32_t)(l4.z & 0xFF) << 16) | ((uint32_t)(l4.w & 0xFF) << 24);
      s32[pass * 256 + tid] = packed;
    }
  }
  __syncthreads();
  int i = blockIdx.x;
  uint32_t li = slab[i];
  uint32_t base = (uint32_t)(i << 13);
  unsigned long long bA = 0, bB = 0, bC = 0, bD = 0;
#pragma unroll 2
  for (int it = 0; it < 8; ++it) {
    int c0 = tid + (it << 10);
    int c1 = c0 + 256;
    int c2 = c0 + 512;
    int c3 = c0 + 768;
    uint32_t l0 = slab[c0], l1 = slab[c1], l2 = slab[c2], l3 = slab[c3];
    uint32_t a0, a1, e0, e1, f0, f1, g0, g1;
    threefry2x32(kn0, kn1, 0u, base + (uint32_t)c0, a0, a1);
    threefry2x32(kn0, kn1, 0u, base + (uint32_t)c1, e0, e1);
    threefry2x32(kn0, kn1, 0u, base + (uint32_t)c2, f0, f1);
    threefry2x32(kn0, kn1, 0u, base + (uint32_t)c3, g0, g1);
    unsigned long long compA = ((unsigned long long)((a0 ^ a1) >> 9) << 32) | (uint32_t)(~c0);
    unsigned long long compB = ((unsigned long long)((e0 ^ e1) >> 9) << 32) | (uint32_t)(~c1);
    unsigned long long compC = ((unsigned long long)((f0 ^ f1) >> 9) << 32) | (uint32_t)(~c2);
    unsigned long long compD = ((unsigned long long)((g0 ^ g1) >> 9) << 32) | (uint32_t)(~c3);
    if (l0 == li) compA = 0;
    if (l1 == li) compB = 0;
    if (l2 == li) compC = 0;
    if (l3 == li) compD = 0;
    if (compA > bA) bA = compA;
    if (compB > bB) bB = compB;
    if (compC > bC) bC = compC;
    if (compD > bD) bD = compD;
  }
  if (bB > bA) bA = bB;
  if (bC > bA) bA = bC;
  if (bD > bA) bA = bD;
  unsigned long long best = bA;
#pragma unroll
  for (int off = 32; off; off >>= 1) {
    unsigned long long o = __shfl_down(best, off);
    if (o > best) best = o;
  }
  int wid = tid >> 6;
  if ((tid & 63) == 0) wmax[wid] = best;
  __syncthreads();
  if (tid == 0) {
    best = wmax[0];
    for (int w = 1; w < 4; ++w) if (wmax[w] > best) best = wmax[w];
    negIdx[i] = best ? (int)(~(uint32_t)best) : -1;
  }
}

// ---------------------------------------------------------------------------
// Kernel 7: positive argmax — bucketed, one wave per row.  (unchanged, proven)
// ---------------------------------------------------------------------------
__global__ __launch_bounds__(256) void posmax_kernel(const int* __restrict__ labels,
                                                     const int* __restrict__ bucketStart,
                                                     const int* __restrict__ bucketIdx,
                                                     uint32_t kp0, uint32_t kp1,
                                                     int* __restrict__ posIdx) {
  int row = blockIdx.x * 4 + (threadIdx.x >> 6);
  int lane = threadIdx.x & 63;
  int cls = labels[row];
  int s = bucketStart[cls], e = bucketStart[cls + 1];
  uint32_t base = (uint32_t)(row << 13);
  unsigned long long best = 0;
  for (int t = s + lane; t < e; t += 64) {
    int cc = bucketIdx[t];
    uint32_t a0, a1;
    threefry2x32(kp0, kp1, 0u, base + (uint32_t)cc, a0, a1);
    uint32_t bits = (a0 ^ a1) >> 9;
    unsigned long long comp = ((unsigned long long)bits << 32) | (uint32_t)(~cc);
    if (cc == row) comp = 0;
    if (comp > best) best = comp;
  }
#pragma unroll
  for (int off = 32; off; off >>= 1) {
    unsigned long long o = __shfl_down(best, off);
    if (o > best) best = o;
  }
  if (lane == 0) posIdx[row] = best ? (int)(~(uint32_t)best) : -1;
}

// ---------------------------------------------------------------------------
// Kernel 8: per-row loss -> per-BLOCK partial (no global atomics; proven).
// ---------------------------------------------------------------------------
__global__ __launch_bounds__(256) void loss_kernel(const float* __restrict__ F,
                                                   const float* __restrict__ H,
                                                   const int* __restrict__ posIdx,
                                                   const int* __restrict__ negIdx,
                                                   float2* __restrict__ lossPart) {
  __shared__ float2 part[4];
  int row = blockIdx.x * 4 + (threadIdx.x >> 6);
  int lane = threadIdx.x & 63;
  int p = posIdx[row], n = negIdx[row];
  bool valid = (p >= 0) && (n >= 0);
  int ps = valid ? p : row;
  int ns = valid ? n : row;
  const float* Fi = F + (size_t)row * DIM;
  const float* Hi = H + (size_t)row * DIM;
  const float* Fp = F + (size_t)ps * DIM;
  const float* Hp = H + (size_t)ps * DIM;
  const float* Fn = F + (size_t)ns * DIM;
  const float* Hn = H + (size_t)ns * DIM;
  float qii = 0.f, qpp = 0.f, qip = 0.f, qnn = 0.f, qin = 0.f;
#pragma unroll
  for (int k = lane * 4; k < DIM; k += 256) {
    float4 fi = *(const float4*)&Fi[k], hi = *(const float4*)&Hi[k];
    float4 fp = *(const float4*)&Fp[k], hp = *(const float4*)&Hp[k];
    float4 fn = *(const float4*)&Fn[k], hn = *(const float4*)&Hn[k];
    qii += fi.x * hi.x + fi.y * hi.y + fi.z * hi.z + fi.w * hi.w;
    qpp += fp.x * hp.x + fp.y * hp.y + fp.z * hp.z + fp.w * hp.w;
    qip += fi.x * hp.x + fi.y * hp.y + fi.z * hp.z + fi.w * hp.w;
    qnn += fn.x * hn.x + fn.y * hn.y + fn.z * hn.z + fn.w * hn.w;
    qin += fi.x * hn.x + fi.y * hn.y + fi.z * hn.z + fi.w * hn.w;
  }
#pragma unroll
  for (int off = 32; off > 0; off >>= 1) {
    qii += __shfl_down(qii, off);
    qpp += __shfl_down(qpp, off);
    qip += __shfl_down(qip, off);
    qnn += __shfl_down(qnn, off);
    qin += __shfl_down(qin, off);
  }
  if (lane == 0) {
    float d2p = fmaxf(qii + qpp - 2.f * qip, 0.f);
    float d2n = fmaxf(qii + qnn - 2.f * qin, 0.f);
    float dpos = sqrtf(d2p + 1e-8f);
    float dneg = sqrtf(d2n + 1e-8f);
    float v = fmaxf(dpos - dneg + 1.0f, 0.0f);
    if (!valid) v = 0.f;
    part[threadIdx.x >> 6] = make_float2(v, valid ? 1.f : 0.f);
  }
  __syncthreads();
  if (threadIdx.x == 0) {
    float s = 0.f, c = 0.f;
#pragma unroll
    for (int w = 0; w < 4; ++w) { s += part[w].x; c += part[w].y; }
    lossPart[blockIdx.x] = make_float2(s, c);
  }
}

// ---------------------------------------------------------------------------
// Kernel 9: finalize — reduce 2048 block partials, single 256-thread block.
// ---------------------------------------------------------------------------
__global__ __launch_bounds__(256) void finalize_kernel(const float2* __restrict__ lossPart,
                                                       float* __restrict__ out) {
  __shared__ float2 wsum[4];
  int tid = threadIdx.x;
  float s = 0.f, c = 0.f;
  for (int z = tid; z < 2048; z += 256) {
    float2 v = lossPart[z];
    s += v.x; c += v.y;
  }
#pragma unroll
  for (int off = 32; off > 0; off >>= 1) {
    s += __shfl_down(s, off);
    c += __shfl_down(c, off);
  }
  if ((tid & 63) == 0) wsum[tid >> 6] = make_float2(s, c);
  __syncthreads();
  if (tid == 0) {
    s = 0.f; c = 0.f;
#pragma unroll
    for (int w = 0; w < 4; ++w) { s += wsum[w].x; c += wsum[w].y; }
    out[0] = s / fmaxf(c, 1.0f);
  }
}

// ---------------------------------------------------------------------------
extern "C" void kernel_launch(void* const* d_in, const int* in_sizes, int n_in,
                              void* d_out, int out_size, void* d_ws, size_t ws_size,
                              hipStream_t stream) {
  const float* F = (const float*)d_in[0];
  const int* labels = (const int*)d_in[1];
  float* out = (float*)d_out;
  char* ws = (char*)d_ws;

  float* S      = (float*)(ws + OFF_S);
  int* bStart   = (int*)(ws + OFF_BSTART);
  int* bIdx     = (int*)(ws + OFF_BIDX);
  int* posIdx   = (int*)(ws + OFF_PIDX);
  int* negIdx   = (int*)(ws + OFF_NIDX);
  float2* lPart = (float2*)(ws + OFF_LPART);
  float* G      = (float*)(ws + OFF_G);
  float* H      = (float*)(ws + OFF_H);
  float* Mpart  = H;   // 16 x 1MB split-K partials, consumed before H written

  // Partitionable (foldlike) split of jax.random.key(42):
  uint32_t kp0, kp1, kn0, kn1;
  threefry2x32(0u, 42u, 0u, 0u, kp0, kp1);
  threefry2x32(0u, 42u, 0u, 1u, kn0, kn1);

  hipMemsetAsync(ws, 0, ZERO_BYTES, stream);

  colsum_kernel<<<256, 256, 0, stream>>>(F, S);

  dim3 covGrid(4, 8, 16);
  covmat_kernel<<<covGrid, 256, 0, stream>>>(F, Mpart);

  buildG_kernel<<<(DIM * DIM) / 256, 256, 0, stream>>>(Mpart, S, G);

  bucket_kernel<<<1, 256, 0, stream>>>(labels, bStart, bIdx);

  negmax_kernel<<<BSZ, 256, 0, stream>>>(labels, kn0, kn1, negIdx);

  posmax_kernel<<<BSZ / 4, 256, 0, stream>>>(labels, bStart, bIdx, kp0, kp1, posIdx);

  dim3 hGrid(DIM / 64, BSZ / 128);
  matmulH_kernel<<<hGrid, 256, 0, stream>>>(F, G, H);

  loss_kernel<<<BSZ / 4, 256, 0, stream>>>(F, H, posIdx, negIdx, lPart);

  finalize_kernel<<<1, 256, 0, stream>>>(lPart, out);
}

// Round 11
// 347.111 us; speedup vs baseline: 2.2688x; 1.1506x over previous
//
#include <hip/hip_runtime.h>
#include <stdint.h>

// Problem constants (fixed by reference): B=8192 samples, D=512 dims, 100 classes.
#define BSZ   8192
#define DIM   512

typedef __attribute__((ext_vector_type(8))) short short8;      // 8 bf16 (4 VGPRs) MFMA A/B frag
typedef __attribute__((ext_vector_type(4))) float f32x4;       // MFMA C/D frag
typedef __attribute__((ext_vector_type(8))) uint16_t u16x8;    // 16B of bf16 payload

// bf16 helpers (RNE; inputs are finite gaussians, no NaN concerns)
__host__ __device__ inline uint16_t f2bf(float x) {
  uint32_t u = __float_as_uint(x);
  return (uint16_t)((u + 0x7FFFu + ((u >> 16) & 1u)) >> 16);
}
__host__ __device__ inline float bf2f(uint16_t h) {
  return __uint_as_float(((uint32_t)h) << 16);
}

// ---------------------------------------------------------------------------
// Threefry-2x32-20 (exact JAX semantics, partitionable mode: bits = y0 ^ y1).
// ---------------------------------------------------------------------------
__host__ __device__ inline uint32_t rotl32(uint32_t v, int s) {
#if defined(__HIP_DEVICE_COMPILE__) && __has_builtin(__builtin_amdgcn_alignbit)
  return __builtin_amdgcn_alignbit(v, v, 32 - s);
#else
  return (v << s) | (v >> (32 - s));
#endif
}

__host__ __device__ inline void threefry2x32(uint32_t k0, uint32_t k1,
                                             uint32_t x0, uint32_t x1,
                                             uint32_t& o0, uint32_t& o1) {
  uint32_t ks2 = k0 ^ k1 ^ 0x1BD11BDAu;
  x0 += k0; x1 += k1;
  x0 += x1; x1 = rotl32(x1, 13); x1 ^= x0;
  x0 += x1; x1 = rotl32(x1, 15); x1 ^= x0;
  x0 += x1; x1 = rotl32(x1, 26); x1 ^= x0;
  x0 += x1; x1 = rotl32(x1,  6); x1 ^= x0;
  x0 += k1; x1 += ks2 + 1u;
  x0 += x1; x1 = rotl32(x1, 17); x1 ^= x0;
  x0 += x1; x1 = rotl32(x1, 29); x1 ^= x0;
  x0 += x1; x1 = rotl32(x1, 16); x1 ^= x0;
  x0 += x1; x1 = rotl32(x1, 24); x1 ^= x0;
  x0 += ks2; x1 += k0 + 2u;
  x0 += x1; x1 = rotl32(x1, 13); x1 ^= x0;
  x0 += x1; x1 = rotl32(x1, 15); x1 ^= x0;
  x0 += x1; x1 = rotl32(x1, 26); x1 ^= x0;
  x0 += x1; x1 = rotl32(x1,  6); x1 ^= x0;
  x0 += k0; x1 += k1 + 3u;
  x0 += x1; x1 = rotl32(x1, 17); x1 ^= x0;
  x0 += x1; x1 = rotl32(x1, 29); x1 ^= x0;
  x0 += x1; x1 = rotl32(x1, 16); x1 ^= x0;
  x0 += x1; x1 = rotl32(x1, 24); x1 ^= x0;
  x0 += k1; x1 += ks2 + 4u;
  x0 += x1; x1 = rotl32(x1, 13); x1 ^= x0;
  x0 += x1; x1 = rotl32(x1, 15); x1 ^= x0;
  x0 += x1; x1 = rotl32(x1, 26); x1 ^= x0;
  x0 += x1; x1 = rotl32(x1,  6); x1 ^= x0;
  x0 += ks2; x1 += k0 + 5u;
  o0 = x0; o1 = x1;
}

// ---------------------------------------------------------------------------
// Workspace layout (bytes), total exactly the proven 18,874,368:
//   small stuff unchanged; Gb (bf16 G) replaces f32 G; Fb (bf16 F, 8 MB) and
//   Hb (bf16 H, 8 MB) fill 2MB..18MB. Mpart (4 x 1MB f32 split-K partials of
//   Fb^T Fb) ALIASES the Hb region — consumed by buildG before matmulH writes.
// ---------------------------------------------------------------------------
constexpr size_t OFF_ACC    = 0;         // legacy, memset
constexpr size_t OFF_S      = 1024;      // 512 f32 column sums
constexpr size_t OFF_BSTART = 3072;      // 101 ints
constexpr size_t OFF_BIDX   = 4096;      // 8192 ints
constexpr size_t OFF_PIDX   = 36864;     // 8192 ints
constexpr size_t OFF_NIDX   = 69632;     // 8192 ints (ends 102400)
constexpr size_t OFF_LPART  = 102400;    // 2048 float2 (ends 118784)
constexpr size_t OFF_GB     = 131072;    // 512x512 bf16 metric (ends 655360)
constexpr size_t OFF_FB     = 2097152;   // 8192x512 bf16 F (ends 10485760)
constexpr size_t OFF_HB     = 10485760;  // 8192x512 bf16 H (ends 18874368)
constexpr size_t ZERO_BYTES = 3072;      // acc + S

// ---------------------------------------------------------------------------
// Kernel 0: F (f32) -> Fb (bf16, RNE). grid 2048 x 256, 8 elems/thread.
// ---------------------------------------------------------------------------
__global__ __launch_bounds__(256) void convert_kernel(const float* __restrict__ F,
                                                      uint16_t* __restrict__ Fb) {
  int i = (blockIdx.x * 256 + threadIdx.x) * 8;
  float4 a = *(const float4*)&F[i];
  float4 b = *(const float4*)&F[i + 4];
  u16x8 o;
  o[0] = f2bf(a.x); o[1] = f2bf(a.y); o[2] = f2bf(a.z); o[3] = f2bf(a.w);
  o[4] = f2bf(b.x); o[5] = f2bf(b.y); o[6] = f2bf(b.z); o[7] = f2bf(b.w);
  *(u16x8*)&Fb[i] = o;
}

// ---------------------------------------------------------------------------
// Kernel 1: column sums S[d] = sum_b F[b][d]  (unchanged, proven; f32 exact)
// ---------------------------------------------------------------------------
__global__ __launch_bounds__(256) void colsum_kernel(const float* __restrict__ F,
                                                     float* __restrict__ S) {
  int b0 = blockIdx.x * 32;
  int t = threadIdx.x;
  float s0 = 0.f, s1 = 0.f;
  for (int r = 0; r < 32; ++r) {
    const float* row = F + (size_t)(b0 + r) * DIM;
    s0 += row[t];
    s1 += row[t + 256];
  }
  atomicAdd(&S[t], s0);
  atomicAdd(&S[t + 256], s1);
}

// ---------------------------------------------------------------------------
// Kernel 2: Mpart[z] = Fb[chunk]^T Fb[chunk] via MFMA 16x16x32 bf16.
// grid (8,8,4), block 256 (4 waves). C-tile 64x64; wave owns a 32x32 quadrant
// (2x2 MFMA tiles). Both LDS tiles transpose-staged from Fb's [k][m] layout
// into [m][k] / [n][k] (frag = one b128). M is symmetric, so any residual
// row/col-swap in the mapping is self-cancelling here.
// Layouts [measured m89/m91/m120]: A m=lane&15,k=quad*8+j; B n=lane&15;
// C/D col=lane&15,row=quad*4+reg.
// ---------------------------------------------------------------------------
__global__ __launch_bounds__(256) void covmat_mfma_kernel(const uint16_t* __restrict__ Fb,
                                                          float* __restrict__ Mpart) {
  __shared__ uint16_t sA[64][40];   // [m][k], stride 80B (16B-aligned, 2-way max)
  __shared__ uint16_t sB[64][40];   // [n][k]
  int i0 = blockIdx.x * 64;
  int j0 = blockIdx.y * 64;
  int kc0 = blockIdx.z * 2048;
  int tid = threadIdx.x;
  int lane = tid & 63, wid = tid >> 6, quad = lane >> 4, l16 = lane & 15;
  int wm = (wid >> 1) * 32;
  int wn = (wid & 1) * 32;
  int sk = tid & 31;          // staging k
  int sm = (tid >> 5) * 8;    // staging m-group
  f32x4 acc[2][2] = {};
  for (int kk = 0; kk < 2048; kk += 32) {
    int krow = kc0 + kk + sk;
    u16x8 va = *(const u16x8*)&Fb[(size_t)krow * DIM + i0 + sm];
    u16x8 vb = *(const u16x8*)&Fb[(size_t)krow * DIM + j0 + sm];
    __syncthreads();   // prev-iter frag reads done before overwrite
#pragma unroll
    for (int jj = 0; jj < 8; ++jj) { sA[sm + jj][sk] = va[jj]; sB[sm + jj][sk] = vb[jj]; }
    __syncthreads();
#pragma unroll
    for (int r = 0; r < 2; ++r) {
      short8 af = *(short8*)&sA[wm + r * 16 + l16][quad * 8];
#pragma unroll
      for (int c = 0; c < 2; ++c) {
        short8 bf = *(short8*)&sB[wn + c * 16 + l16][quad * 8];
        acc[r][c] = __builtin_amdgcn_mfma_f32_16x16x32_bf16(af, bf, acc[r][c], 0, 0, 0);
      }
    }
  }
  float* out = Mpart + (size_t)blockIdx.z * DIM * DIM;
#pragma unroll
  for (int r = 0; r < 2; ++r)
#pragma unroll
    for (int c = 0; c < 2; ++c)
#pragma unroll
      for (int g = 0; g < 4; ++g)
        out[(size_t)(i0 + wm + r * 16 + quad * 4 + g) * DIM + j0 + wn + c * 16 + l16] = acc[r][c][g];
}

// ---------------------------------------------------------------------------
// Kernel 3: Gb = bf16( (sum_z Mpart[z])/B - mean mean^T + I )
// ---------------------------------------------------------------------------
__global__ __launch_bounds__(256) void buildG_kernel(const float* __restrict__ Mpart,
                                                     const float* __restrict__ S,
                                                     uint16_t* __restrict__ Gb) {
  int idx = blockIdx.x * 256 + threadIdx.x;
  int i = idx >> 9, j = idx & 511;
  float m = Mpart[idx] + Mpart[(size_t)DIM * DIM + idx] +
            Mpart[2 * (size_t)DIM * DIM + idx] + Mpart[3 * (size_t)DIM * DIM + idx];
  const float invB = 1.0f / (float)BSZ;
  float mi = S[i] * invB, mj = S[j] * invB;
  float g = m * invB - mi * mj + (i == j ? 1.0f : 0.0f);
  Gb[idx] = f2bf(g);
}

// ---------------------------------------------------------------------------
// Kernel 4: Hb = bf16( Fb * Gb ) via MFMA. grid (8, 64), block 256 (4 waves).
// Tile 128(m) x 64(n); wave owns 32 rows x 64 cols = 2x4 MFMA tiles. A staged
// [m][k] by direct b128 copy (Fb is row-major, k contiguous); B (Gb) staged
// transposed into [n][k]. KB=64 (two k32 steps per stage).
// ---------------------------------------------------------------------------
__global__ __launch_bounds__(256) void matmulH_mfma_kernel(const uint16_t* __restrict__ Fb,
                                                           const uint16_t* __restrict__ Gb,
                                                           uint16_t* __restrict__ Hb) {
  __shared__ uint16_t sA[128][72];   // [m][k], stride 144B (16B-aligned, 2-way max)
  __shared__ uint16_t sB[64][72];    // [n][k]
  int n0 = blockIdx.x * 64;
  int m0 = blockIdx.y * 128;
  int tid = threadIdx.x;
  int lane = tid & 63, wid = tid >> 6, quad = lane >> 4, l16 = lane & 15;
  int am = tid & 127, ah = (tid >> 7) * 32;    // A staging: row, k-half
  int bk = tid >> 2, bn = (tid & 3) * 16;      // B staging: k, n-group
  f32x4 acc[2][4] = {};
  for (int k0 = 0; k0 < DIM; k0 += 64) {
    __syncthreads();
    {
      const uint16_t* src = &Fb[(size_t)(m0 + am) * DIM + k0 + ah];
#pragma unroll
      for (int v = 0; v < 4; ++v)
        *(u16x8*)&sA[am][ah + v * 8] = *(const u16x8*)&src[v * 8];
    }
    {
      u16x8 g0 = *(const u16x8*)&Gb[(size_t)(k0 + bk) * DIM + n0 + bn];
      u16x8 g1 = *(const u16x8*)&Gb[(size_t)(k0 + bk) * DIM + n0 + bn + 8];
#pragma unroll
      for (int jj = 0; jj < 8; ++jj) { sB[bn + jj][bk] = g0[jj]; sB[bn + 8 + jj][bk] = g1[jj]; }
    }
    __syncthreads();
#pragma unroll
    for (int k32 = 0; k32 < 64; k32 += 32) {
      short8 af[2];
#pragma unroll
      for (int r = 0; r < 2; ++r)
        af[r] = *(short8*)&sA[wid * 32 + r * 16 + l16][k32 + quad * 8];
#pragma unroll
      for (int c = 0; c < 4; ++c) {
        short8 bf = *(short8*)&sB[c * 16 + l16][k32 + quad * 8];
#pragma unroll
        for (int r = 0; r < 2; ++r)
          acc[r][c] = __builtin_amdgcn_mfma_f32_16x16x32_bf16(af[r], bf, acc[r][c], 0, 0, 0);
      }
    }
  }
#pragma unroll
  for (int r = 0; r < 2; ++r)
#pragma unroll
    for (int c = 0; c < 4; ++c)
#pragma unroll
      for (int g = 0; g < 4; ++g) {
        int row = m0 + wid * 32 + r * 16 + quad * 4 + g;
        int col = n0 + c * 16 + l16;
        Hb[(size_t)row * DIM + col] = f2bf(acc[r][c][g]);
      }
}

// ---------------------------------------------------------------------------
// Kernel 5: class buckets (single block).  (unchanged, proven)
// ---------------------------------------------------------------------------
__global__ __launch_bounds__(256) void bucket_kernel(const int* __restrict__ labels,
                                                     int* __restrict__ bucketStart,
                                                     int* __restrict__ bucketIdx) {
  __shared__ int cnt[128];
  __shared__ int base[128];
  int tid = threadIdx.x;
  if (tid < 128) cnt[tid] = 0;
  __syncthreads();
  for (int b = tid; b < BSZ; b += 256) atomicAdd(&cnt[labels[b]], 1);
  __syncthreads();
  if (tid == 0) {
    int run = 0;
    for (int c = 0; c < 100; ++c) { base[c] = run; bucketStart[c] = run; run += cnt[c]; }
    bucketStart[100] = run;
  }
  __syncthreads();
  for (int b = tid; b < BSZ; b += 256) {
    int p = atomicAdd(&base[labels[b]], 1);
    bucketIdx[p] = b;
  }
}

// ---------------------------------------------------------------------------
// Kernel 6: negative argmax — BYTE-IDENTICAL to r10 (int-issue-bound at
// ~188 us; 67.1M irreducible threefry hashes x ~72 int ops at the measured
// half-rate int VALU; three structures all land at the same rate).
// ---------------------------------------------------------------------------
__global__ __launch_bounds__(256) void negmax_kernel(const int* __restrict__ labels,
                                                     uint32_t kn0, uint32_t kn1,
                                                     int* __restrict__ negIdx) {
  __shared__ __align__(16) uint8_t slab[BSZ];
  __shared__ unsigned long long wmax[4];
  int tid = threadIdx.x;
  {
    uint32_t* s32 = (uint32_t*)slab;
#pragma unroll
    for (int pass = 0; pass < 8; ++pass) {
      int idx = pass * 1024 + tid * 4;
      int4 l4 = *(const int4*)&labels[idx];
      uint32_t packed = (uint32_t)(l4.x & 0xFF) | ((uint32_t)(l4.y & 0xFF) << 8) |
                        ((uint32_t)(l4.z & 0xFF) << 16) | ((uint32_t)(l4.w & 0xFF) << 24);
      s32[pass * 256 + tid] = packed;
    }
  }
  __syncthreads();
  int i = blockIdx.x;
  uint32_t li = slab[i];
  uint32_t base = (uint32_t)(i << 13);
  unsigned long long bA = 0, bB = 0, bC = 0, bD = 0;
#pragma unroll 2
  for (int it = 0; it < 8; ++it) {
    int c0 = tid + (it << 10);
    int c1 = c0 + 256;
    int c2 = c0 + 512;
    int c3 = c0 + 768;
    uint32_t l0 = slab[c0], l1 = slab[c1], l2 = slab[c2], l3 = slab[c3];
    uint32_t a0, a1, e0, e1, f0, f1, g0, g1;
    threefry2x32(kn0, kn1, 0u, base + (uint32_t)c0, a0, a1);
    threefry2x32(kn0, kn1, 0u, base + (uint32_t)c1, e0, e1);
    threefry2x32(kn0, kn1, 0u, base + (uint32_t)c2, f0, f1);
    threefry2x32(kn0, kn1, 0u, base + (uint32_t)c3, g0, g1);
    unsigned long long compA = ((unsigned long long)((a0 ^ a1) >> 9) << 32) | (uint32_t)(~c0);
    unsigned long long compB = ((unsigned long long)((e0 ^ e1) >> 9) << 32) | (uint32_t)(~c1);
    unsigned long long compC = ((unsigned long long)((f0 ^ f1) >> 9) << 32) | (uint32_t)(~c2);
    unsigned long long compD = ((unsigned long long)((g0 ^ g1) >> 9) << 32) | (uint32_t)(~c3);
    if (l0 == li) compA = 0;
    if (l1 == li) compB = 0;
    if (l2 == li) compC = 0;
    if (l3 == li) compD = 0;
    if (compA > bA) bA = compA;
    if (compB > bB) bB = compB;
    if (compC > bC) bC = compC;
    if (compD > bD) bD = compD;
  }
  if (bB > bA) bA = bB;
  if (bC > bA) bA = bC;
  if (bD > bA) bA = bD;
  unsigned long long best = bA;
#pragma unroll
  for (int off = 32; off; off >>= 1) {
    unsigned long long o = __shfl_down(best, off);
    if (o > best) best = o;
  }
  int wid = tid >> 6;
  if ((tid & 63) == 0) wmax[wid] = best;
  __syncthreads();
  if (tid == 0) {
    best = wmax[0];
    for (int w = 1; w < 4; ++w) if (wmax[w] > best) best = wmax[w];
    negIdx[i] = best ? (int)(~(uint32_t)best) : -1;
  }
}

// ---------------------------------------------------------------------------
// Kernel 7: positive argmax — bucketed, one wave per row.  (unchanged, proven)
// ---------------------------------------------------------------------------
__global__ __launch_bounds__(256) void posmax_kernel(const int* __restrict__ labels,
                                                     const int* __restrict__ bucketStart,
                                                     const int* __restrict__ bucketIdx,
                                                     uint32_t kp0, uint32_t kp1,
                                                     int* __restrict__ posIdx) {
  int row = blockIdx.x * 4 + (threadIdx.x >> 6);
  int lane = threadIdx.x & 63;
  int cls = labels[row];
  int s = bucketStart[cls], e = bucketStart[cls + 1];
  uint32_t base = (uint32_t)(row << 13);
  unsigned long long best = 0;
  for (int t = s + lane; t < e; t += 64) {
    int cc = bucketIdx[t];
    uint32_t a0, a1;
    threefry2x32(kp0, kp1, 0u, base + (uint32_t)cc, a0, a1);
    uint32_t bits = (a0 ^ a1) >> 9;
    unsigned long long comp = ((unsigned long long)bits << 32) | (uint32_t)(~cc);
    if (cc == row) comp = 0;
    if (comp > best) best = comp;
  }
#pragma unroll
  for (int off = 32; off; off >>= 1) {
    unsigned long long o = __shfl_down(best, off);
    if (o > best) best = o;
  }
  if (lane == 0) posIdx[row] = best ? (int)(~(uint32_t)best) : -1;
}

// ---------------------------------------------------------------------------
// Kernel 8: per-row loss -> per-BLOCK partial. H is now bf16; one shot per
// lane (8 elems, 64 lanes x 8 = 512 = DIM). No global atomics (proven).
// ---------------------------------------------------------------------------
__global__ __launch_bounds__(256) void loss_kernel(const float* __restrict__ F,
                                                   const uint16_t* __restrict__ Hb,
                                                   const int* __restrict__ posIdx,
                                                   const int* __restrict__ negIdx,
                                                   float2* __restrict__ lossPart) {
  __shared__ float2 part[4];
  int row = blockIdx.x * 4 + (threadIdx.x >> 6);
  int lane = threadIdx.x & 63;
  int p = posIdx[row], n = negIdx[row];
  bool valid = (p >= 0) && (n >= 0);
  int ps = valid ? p : row;
  int ns = valid ? n : row;
  int k = lane * 8;
  const float* Fi = F + (size_t)row * DIM + k;
  const float* Fp = F + (size_t)ps * DIM + k;
  const float* Fn = F + (size_t)ns * DIM + k;
  const uint16_t* Hi = Hb + (size_t)row * DIM + k;
  const uint16_t* Hp = Hb + (size_t)ps * DIM + k;
  const uint16_t* Hn = Hb + (size_t)ns * DIM + k;
  float4 fi0 = *(const float4*)&Fi[0], fi1 = *(const float4*)&Fi[4];
  float4 fp0 = *(const float4*)&Fp[0], fp1 = *(const float4*)&Fp[4];
  float4 fn0 = *(const float4*)&Fn[0], fn1 = *(const float4*)&Fn[4];
  u16x8 h_i = *(const u16x8*)Hi;
  u16x8 h_p = *(const u16x8*)Hp;
  u16x8 h_n = *(const u16x8*)Hn;
  float fi[8] = {fi0.x, fi0.y, fi0.z, fi0.w, fi1.x, fi1.y, fi1.z, fi1.w};
  float fp[8] = {fp0.x, fp0.y, fp0.z, fp0.w, fp1.x, fp1.y, fp1.z, fp1.w};
  float fn[8] = {fn0.x, fn0.y, fn0.z, fn0.w, fn1.x, fn1.y, fn1.z, fn1.w};
  float qii = 0.f, qpp = 0.f, qip = 0.f, qnn = 0.f, qin = 0.f;
#pragma unroll
  for (int jj = 0; jj < 8; ++jj) {
    float hi = bf2f(h_i[jj]), hp = bf2f(h_p[jj]), hn = bf2f(h_n[jj]);
    qii += fi[jj] * hi;
    qpp += fp[jj] * hp;
    qip += fi[jj] * hp;
    qnn += fn[jj] * hn;
    qin += fi[jj] * hn;
  }
#pragma unroll
  for (int off = 32; off > 0; off >>= 1) {
    qii += __shfl_down(qii, off);
    qpp += __shfl_down(qpp, off);
    qip += __shfl_down(qip, off);
    qnn += __shfl_down(qnn, off);
    qin += __shfl_down(qin, off);
  }
  if (lane == 0) {
    float d2p = fmaxf(qii + qpp - 2.f * qip, 0.f);
    float d2n = fmaxf(qii + qnn - 2.f * qin, 0.f);
    float dpos = sqrtf(d2p + 1e-8f);
    float dneg = sqrtf(d2n + 1e-8f);
    float v = fmaxf(dpos - dneg + 1.0f, 0.0f);
    if (!valid) v = 0.f;
    part[threadIdx.x >> 6] = make_float2(v, valid ? 1.f : 0.f);
  }
  __syncthreads();
  if (threadIdx.x == 0) {
    float s = 0.f, c = 0.f;
#pragma unroll
    for (int w = 0; w < 4; ++w) { s += part[w].x; c += part[w].y; }
    lossPart[blockIdx.x] = make_float2(s, c);
  }
}

// ---------------------------------------------------------------------------
// Kernel 9: finalize — reduce 2048 block partials, single 256-thread block.
// ---------------------------------------------------------------------------
__global__ __launch_bounds__(256) void finalize_kernel(const float2* __restrict__ lossPart,
                                                       float* __restrict__ out) {
  __shared__ float2 wsum[4];
  int tid = threadIdx.x;
  float s = 0.f, c = 0.f;
  for (int z = tid; z < 2048; z += 256) {
    float2 v = lossPart[z];
    s += v.x; c += v.y;
  }
#pragma unroll
  for (int off = 32; off > 0; off >>= 1) {
    s += __shfl_down(s, off);
    c += __shfl_down(c, off);
  }
  if ((tid & 63) == 0) wsum[tid >> 6] = make_float2(s, c);
  __syncthreads();
  if (tid == 0) {
    s = 0.f; c = 0.f;
#pragma unroll
    for (int w = 0; w < 4; ++w) { s += wsum[w].x; c += wsum[w].y; }
    out[0] = s / fmaxf(c, 1.0f);
  }
}

// ---------------------------------------------------------------------------
extern "C" void kernel_launch(void* const* d_in, const int* in_sizes, int n_in,
                              void* d_out, int out_size, void* d_ws, size_t ws_size,
                              hipStream_t stream) {
  const float* F = (const float*)d_in[0];
  const int* labels = (const int*)d_in[1];
  float* out = (float*)d_out;
  char* ws = (char*)d_ws;

  float* S       = (float*)(ws + OFF_S);
  int* bStart    = (int*)(ws + OFF_BSTART);
  int* bIdx      = (int*)(ws + OFF_BIDX);
  int* posIdx    = (int*)(ws + OFF_PIDX);
  int* negIdx    = (int*)(ws + OFF_NIDX);
  float2* lPart  = (float2*)(ws + OFF_LPART);
  uint16_t* Gb   = (uint16_t*)(ws + OFF_GB);
  uint16_t* Fb   = (uint16_t*)(ws + OFF_FB);
  uint16_t* Hb   = (uint16_t*)(ws + OFF_HB);
  float* Mpart   = (float*)(ws + OFF_HB);   // 4x1MB, consumed before Hb written

  // Partitionable (foldlike) split of jax.random.key(42):
  uint32_t kp0, kp1, kn0, kn1;
  threefry2x32(0u, 42u, 0u, 0u, kp0, kp1);
  threefry2x32(0u, 42u, 0u, 1u, kn0, kn1);

  hipMemsetAsync(ws, 0, ZERO_BYTES, stream);

  convert_kernel<<<2048, 256, 0, stream>>>(F, Fb);

  colsum_kernel<<<256, 256, 0, stream>>>(F, S);

  dim3 covGrid(8, 8, 4);
  covmat_mfma_kernel<<<covGrid, 256, 0, stream>>>(Fb, Mpart);

  buildG_kernel<<<(DIM * DIM) / 256, 256, 0, stream>>>(Mpart, S, Gb);

  bucket_kernel<<<1, 256, 0, stream>>>(labels, bStart, bIdx);

  negmax_kernel<<<BSZ, 256, 0, stream>>>(labels, kn0, kn1, negIdx);

  posmax_kernel<<<BSZ / 4, 256, 0, stream>>>(labels, bStart, bIdx, kp0, kp1, posIdx);

  dim3 hGrid(8, 64);
  matmulH_mfma_kernel<<<hGrid, 256, 0, stream>>>(Fb, Gb, Hb);

  loss_kernel<<<BSZ / 4, 256, 0, stream>>>(F, Hb, posIdx, negIdx, lPart);

  finalize_kernel<<<1, 256, 0, stream>>>(lPart, out);
}

// Round 13
// 332.111 us; speedup vs baseline: 2.3713x; 1.0452x over previous
//
#include <hip/hip_runtime.h>
#include <stdint.h>

// Problem constants (fixed by reference): B=8192 samples, D=512 dims, 100 classes.
#define BSZ   8192
#define DIM   512

typedef __attribute__((ext_vector_type(8))) short short8;      // 8 bf16 MFMA A/B frag
typedef __attribute__((ext_vector_type(4))) float f32x4;       // MFMA C/D frag
typedef __attribute__((ext_vector_type(8))) uint16_t u16x8;    // 16B of bf16 payload

__host__ __device__ inline uint16_t f2bf(float x) {
  uint32_t u = __float_as_uint(x);
  return (uint16_t)((u + 0x7FFFu + ((u >> 16) & 1u)) >> 16);
}
__host__ __device__ inline float bf2f(uint16_t h) {
  return __uint_as_float(((uint32_t)h) << 16);
}

// ---------------------------------------------------------------------------
// Threefry-2x32-20 (exact JAX semantics, partitionable mode: bits = y0 ^ y1).
// ---------------------------------------------------------------------------
__host__ __device__ inline uint32_t rotl32(uint32_t v, int s) {
#if defined(__HIP_DEVICE_COMPILE__) && __has_builtin(__builtin_amdgcn_alignbit)
  return __builtin_amdgcn_alignbit(v, v, 32 - s);
#else
  return (v << s) | (v >> (32 - s));
#endif
}

__host__ __device__ inline void threefry2x32(uint32_t k0, uint32_t k1,
                                             uint32_t x0, uint32_t x1,
                                             uint32_t& o0, uint32_t& o1) {
  uint32_t ks2 = k0 ^ k1 ^ 0x1BD11BDAu;
  x0 += k0; x1 += k1;
  x0 += x1; x1 = rotl32(x1, 13); x1 ^= x0;
  x0 += x1; x1 = rotl32(x1, 15); x1 ^= x0;
  x0 += x1; x1 = rotl32(x1, 26); x1 ^= x0;
  x0 += x1; x1 = rotl32(x1,  6); x1 ^= x0;
  x0 += k1; x1 += ks2 + 1u;
  x0 += x1; x1 = rotl32(x1, 17); x1 ^= x0;
  x0 += x1; x1 = rotl32(x1, 29); x1 ^= x0;
  x0 += x1; x1 = rotl32(x1, 16); x1 ^= x0;
  x0 += x1; x1 = rotl32(x1, 24); x1 ^= x0;
  x0 += ks2; x1 += k0 + 2u;
  x0 += x1; x1 = rotl32(x1, 13); x1 ^= x0;
  x0 += x1; x1 = rotl32(x1, 15); x1 ^= x0;
  x0 += x1; x1 = rotl32(x1, 26); x1 ^= x0;
  x0 += x1; x1 = rotl32(x1,  6); x1 ^= x0;
  x0 += k0; x1 += k1 + 3u;
  x0 += x1; x1 = rotl32(x1, 17); x1 ^= x0;
  x0 += x1; x1 = rotl32(x1, 29); x1 ^= x0;
  x0 += x1; x1 = rotl32(x1, 16); x1 ^= x0;
  x0 += x1; x1 = rotl32(x1, 24); x1 ^= x0;
  x0 += k1; x1 += ks2 + 4u;
  x0 += x1; x1 = rotl32(x1, 13); x1 ^= x0;
  x0 += x1; x1 = rotl32(x1, 15); x1 ^= x0;
  x0 += x1; x1 = rotl32(x1, 26); x1 ^= x0;
  x0 += x1; x1 = rotl32(x1,  6); x1 ^= x0;
  x0 += ks2; x1 += k0 + 5u;
  o0 = x0; o1 = x1;
}

// ---------------------------------------------------------------------------
// Workspace layout (bytes), r11-proven, plus rowCtr at offset 0.
// Mpart (4 x 1 MB f32 split-K) ALIASES Hb: consumed by buildG before the
// overlap kernel writes Hb.
// ---------------------------------------------------------------------------
constexpr size_t OFF_CTR    = 0;         // 1 int (work-steal counter), zeroed
constexpr size_t OFF_S      = 1024;      // 512 f32, zeroed
constexpr size_t OFF_BSTART = 3072;      // 101 ints
constexpr size_t OFF_BIDX   = 4096;      // 8192 ints
constexpr size_t OFF_PIDX   = 36864;     // 8192 ints
constexpr size_t OFF_NIDX   = 69632;     // 8192 ints (ends 102400)
constexpr size_t OFF_LPART  = 102400;    // 2048 float2 (ends 118784)
constexpr size_t OFF_GB     = 131072;    // 512x512 bf16 metric
constexpr size_t OFF_FB     = 2097152;   // 8192x512 bf16 F (8 MB)
constexpr size_t OFF_HB     = 10485760;  // 8192x512 bf16 H (8 MB) / Mpart alias
constexpr size_t ZERO_BYTES = 3072;      // ctr + S

// ---------------------------------------------------------------------------
// Kernel 1: prep — convert F->Fb (all 2048 blocks) + colsum (blocks 0..255).
// Both bodies byte-proven (r11 convert_kernel / colsum_kernel).
// ---------------------------------------------------------------------------
__global__ __launch_bounds__(256) void prep_kernel(const float* __restrict__ F,
                                                   uint16_t* __restrict__ Fb,
                                                   float* __restrict__ S) {
  int i = (blockIdx.x * 256 + threadIdx.x) * 8;
  float4 a = *(const float4*)&F[i];
  float4 b = *(const float4*)&F[i + 4];
  u16x8 o;
  o[0] = f2bf(a.x); o[1] = f2bf(a.y); o[2] = f2bf(a.z); o[3] = f2bf(a.w);
  o[4] = f2bf(b.x); o[5] = f2bf(b.y); o[6] = f2bf(b.z); o[7] = f2bf(b.w);
  *(u16x8*)&Fb[i] = o;
  if (blockIdx.x < 256) {
    int b0 = blockIdx.x * 32;
    int t = threadIdx.x;
    float s0 = 0.f, s1 = 0.f;
    for (int r = 0; r < 32; ++r) {
      const float* row = F + (size_t)(b0 + r) * DIM;
      s0 += row[t];
      s1 += row[t + 256];
    }
    atomicAdd(&S[t], s0);
    atomicAdd(&S[t + 256], s1);
  }
}

// ---------------------------------------------------------------------------
// Kernel 2: covmat via MFMA (r11 proven, verbatim). grid (8,8,4).
// ---------------------------------------------------------------------------
__global__ __launch_bounds__(256) void covmat_mfma_kernel(const uint16_t* __restrict__ Fb,
                                                          float* __restrict__ Mpart) {
  __shared__ uint16_t sA[64][40];
  __shared__ uint16_t sB[64][40];
  int i0 = blockIdx.x * 64;
  int j0 = blockIdx.y * 64;
  int kc0 = blockIdx.z * 2048;
  int tid = threadIdx.x;
  int lane = tid & 63, wid = tid >> 6, quad = lane >> 4, l16 = lane & 15;
  int wm = (wid >> 1) * 32;
  int wn = (wid & 1) * 32;
  int sk = tid & 31;
  int sm = (tid >> 5) * 8;
  f32x4 acc[2][2] = {};
  for (int kk = 0; kk < 2048; kk += 32) {
    int krow = kc0 + kk + sk;
    u16x8 va = *(const u16x8*)&Fb[(size_t)krow * DIM + i0 + sm];
    u16x8 vb = *(const u16x8*)&Fb[(size_t)krow * DIM + j0 + sm];
    __syncthreads();
#pragma unroll
    for (int jj = 0; jj < 8; ++jj) { sA[sm + jj][sk] = va[jj]; sB[sm + jj][sk] = vb[jj]; }
    __syncthreads();
#pragma unroll
    for (int r = 0; r < 2; ++r) {
      short8 af = *(short8*)&sA[wm + r * 16 + l16][quad * 8];
#pragma unroll
      for (int c = 0; c < 2; ++c) {
        short8 bf = *(short8*)&sB[wn + c * 16 + l16][quad * 8];
        acc[r][c] = __builtin_amdgcn_mfma_f32_16x16x32_bf16(af, bf, acc[r][c], 0, 0, 0);
      }
    }
  }
  float* out = Mpart + (size_t)blockIdx.z * DIM * DIM;
#pragma unroll
  for (int r = 0; r < 2; ++r)
#pragma unroll
    for (int c = 0; c < 2; ++c)
#pragma unroll
      for (int g = 0; g < 4; ++g)
        out[(size_t)(i0 + wm + r * 16 + quad * 4 + g) * DIM + j0 + wn + c * 16 + l16] = acc[r][c][g];
}

// ---------------------------------------------------------------------------
// Kernel 3: buildG (r11 proven, verbatim).
// ---------------------------------------------------------------------------
__global__ __launch_bounds__(256) void buildG_kernel(const float* __restrict__ Mpart,
                                                     const float* __restrict__ S,
                                                     uint16_t* __restrict__ Gb) {
  int idx = blockIdx.x * 256 + threadIdx.x;
  int i = idx >> 9, j = idx & 511;
  float m = Mpart[idx] + Mpart[(size_t)DIM * DIM + idx] +
            Mpart[2 * (size_t)DIM * DIM + idx] + Mpart[3 * (size_t)DIM * DIM + idx];
  const float invB = 1.0f / (float)BSZ;
  float mi = S[i] * invB, mj = S[j] * invB;
  Gb[idx] = f2bf(m * invB - mi * mj + (i == j ? 1.0f : 0.0f));
}

// ---------------------------------------------------------------------------
// Kernel 4: class buckets (r7 proven, verbatim).
// ---------------------------------------------------------------------------
__global__ __launch_bounds__(256) void bucket_kernel(const int* __restrict__ labels,
                                                     int* __restrict__ bucketStart,
                                                     int* __restrict__ bucketIdx) {
  __shared__ int cnt[128];
  __shared__ int base[128];
  int tid = threadIdx.x;
  if (tid < 128) cnt[tid] = 0;
  __syncthreads();
  for (int b = tid; b < BSZ; b += 256) atomicAdd(&cnt[labels[b]], 1);
  __syncthreads();
  if (tid == 0) {
    int run = 0;
    for (int c = 0; c < 100; ++c) { base[c] = run; bucketStart[c] = run; run += cnt[c]; }
    bucketStart[100] = run;
  }
  __syncthreads();
  for (int b = tid; b < BSZ; b += 256) {
    int p = atomicAdd(&base[labels[b]], 1);
    bucketIdx[p] = b;
  }
}

// ---------------------------------------------------------------------------
// Kernel 5: OVERLAP — ordinary (non-cooperative) kernel, no cross-block deps:
// all inputs (Fb, Gb, bStart/bIdx, labels) are complete at launch.
//   blocks [0,224):   matmulH MFMA over 512 tiles (strided) [r11 body]
//   blocks [224,256): posmax over 64 rows/wave               [r7 body]
//   blocks [256,1024): negmax immediately
// After role A/B work, blocks JOIN negmax via global atomic row counter —
// no idle blocks; matmul MFMA cycles co-schedule under negmax int-VALU (m114).
// ---------------------------------------------------------------------------
struct SharedMM  { uint16_t sA[128][72]; uint16_t sB[64][72]; };            // 27,648 B
struct SharedNeg { uint8_t slab[BSZ]; unsigned long long wmax[4]; int curRow; };
union __align__(16) SharedU { SharedMM mm; SharedNeg neg; };

__global__ __launch_bounds__(256) void overlap_kernel(
    const uint16_t* __restrict__ Fb, const uint16_t* __restrict__ Gb,
    uint16_t* __restrict__ Hb, const int* __restrict__ labels,
    const int* __restrict__ bStart, const int* __restrict__ bIdx,
    int* __restrict__ posIdx, int* __restrict__ negIdx,
    int* __restrict__ rowCtr,
    uint32_t kp0, uint32_t kp1, uint32_t kn0, uint32_t kn1) {
  __shared__ SharedU sh;
  int bid = blockIdx.x, tid = threadIdx.x;
  int lane = tid & 63, wid = tid >> 6, quad = lane >> 4, l16 = lane & 15;

  if (bid < 224) {
    // ---- Role A: matmulH, r11-proven body, 512 tiles strided by 224.
    int am = tid & 127, ah = (tid >> 7) * 32;
    int bk = tid >> 2, bn = (tid & 3) * 16;
    int tm = wid * 32;
    for (int t = bid; t < 512; t += 224) {
      int n0 = (t & 7) * 64;
      int m0 = (t >> 3) * 128;
      f32x4 acc[2][4] = {};
      for (int k0 = 0; k0 < DIM; k0 += 64) {
        {
          const uint16_t* src = &Fb[(size_t)(m0 + am) * DIM + k0 + ah];
#pragma unroll
          for (int v = 0; v < 4; ++v)
            *(u16x8*)&sh.mm.sA[am][ah + v * 8] = *(const u16x8*)&src[v * 8];
        }
        {
          u16x8 g0 = *(const u16x8*)&Gb[(size_t)(k0 + bk) * DIM + n0 + bn];
          u16x8 g1 = *(const u16x8*)&Gb[(size_t)(k0 + bk) * DIM + n0 + bn + 8];
#pragma unroll
          for (int jj = 0; jj < 8; ++jj) { sh.mm.sB[bn + jj][bk] = g0[jj]; sh.mm.sB[bn + 8 + jj][bk] = g1[jj]; }
        }
        __syncthreads();
#pragma unroll
        for (int k32 = 0; k32 < 64; k32 += 32) {
          short8 af[2];
#pragma unroll
          for (int r = 0; r < 2; ++r)
            af[r] = *(short8*)&sh.mm.sA[tm + r * 16 + l16][k32 + quad * 8];
#pragma unroll
          for (int c = 0; c < 4; ++c) {
            short8 bf = *(short8*)&sh.mm.sB[c * 16 + l16][k32 + quad * 8];
#pragma unroll
            for (int r = 0; r < 2; ++r)
              acc[r][c] = __builtin_amdgcn_mfma_f32_16x16x32_bf16(af[r], bf, acc[r][c], 0, 0, 0);
          }
        }
        __syncthreads();
      }
#pragma unroll
      for (int r = 0; r < 2; ++r)
#pragma unroll
        for (int c = 0; c < 4; ++c)
#pragma unroll
          for (int g = 0; g < 4; ++g)
            Hb[(size_t)(m0 + tm + r * 16 + quad * 4 + g) * DIM + n0 + c * 16 + l16] = f2bf(acc[r][c][g]);
    }
    __syncthreads();   // role done; LDS handoff to neg slab
  } else if (bid < 256) {
    // ---- Role B: posmax, r7-proven body, 64 rows per wave.
    for (int row = (bid - 224) * 4 + wid; row < BSZ; row += 128) {
      int cls = labels[row];
      int s = bStart[cls], e = bStart[cls + 1];
      uint32_t base = (uint32_t)(row << 13);
      unsigned long long best = 0;
      for (int t2 = s + lane; t2 < e; t2 += 64) {
        int cc = bIdx[t2];
        uint32_t a0, a1;
        threefry2x32(kp0, kp1, 0u, base + (uint32_t)cc, a0, a1);
        unsigned long long comp = ((unsigned long long)((a0 ^ a1) >> 9) << 32) | (uint32_t)(~cc);
        if (cc == row) comp = 0;
        if (comp > best) best = comp;
      }
#pragma unroll
      for (int off = 32; off; off >>= 1) {
        unsigned long long o = __shfl_down(best, off);
        if (o > best) best = o;
      }
      if (lane == 0) posIdx[row] = best ? (int)(~(uint32_t)best) : -1;
    }
    __syncthreads();
  }

  // ---- All blocks: negmax over work-stolen rows (r10-proven per-row body).
  {
    uint32_t* s32 = (uint32_t*)sh.neg.slab;
#pragma unroll
    for (int pass = 0; pass < 8; ++pass) {
      int idx = pass * 1024 + tid * 4;
      int4 l4 = *(const int4*)&labels[idx];
      uint32_t packed = (uint32_t)(l4.x & 0xFF) | ((uint32_t)(l4.y & 0xFF) << 8) |
                        ((uint32_t)(l4.z & 0xFF) << 16) | ((uint32_t)(l4.w & 0xFF) << 24);
      s32[pass * 256 + tid] = packed;
    }
  }
  __syncthreads();
  while (true) {
    if (tid == 0) sh.neg.curRow = atomicAdd(rowCtr, 1);
    __syncthreads();
    int row = sh.neg.curRow;
    if (row >= BSZ) break;
    uint32_t li = sh.neg.slab[row];
    uint32_t base = (uint32_t)(row << 13);
    unsigned long long bA = 0, bB = 0, bC = 0, bD = 0;
#pragma unroll 2
    for (int it = 0; it < 8; ++it) {
      int c0 = tid + (it << 10);
      int c1 = c0 + 256, c2 = c0 + 512, c3 = c0 + 768;
      uint32_t l0 = sh.neg.slab[c0], l1 = sh.neg.slab[c1], l2 = sh.neg.slab[c2], l3 = sh.neg.slab[c3];
      uint32_t a0, a1, e0, e1, f0, f1, g0, g1;
      threefry2x32(kn0, kn1, 0u, base + (uint32_t)c0, a0, a1);
      threefry2x32(kn0, kn1, 0u, base + (uint32_t)c1, e0, e1);
      threefry2x32(kn0, kn1, 0u, base + (uint32_t)c2, f0, f1);
      threefry2x32(kn0, kn1, 0u, base + (uint32_t)c3, g0, g1);
      unsigned long long compA = ((unsigned long long)((a0 ^ a1) >> 9) << 32) | (uint32_t)(~c0);
      unsigned long long compB = ((unsigned long long)((e0 ^ e1) >> 9) << 32) | (uint32_t)(~c1);
      unsigned long long compC = ((unsigned long long)((f0 ^ f1) >> 9) << 32) | (uint32_t)(~c2);
      unsigned long long compD = ((unsigned long long)((g0 ^ g1) >> 9) << 32) | (uint32_t)(~c3);
      if (l0 == li) compA = 0;
      if (l1 == li) compB = 0;
      if (l2 == li) compC = 0;
      if (l3 == li) compD = 0;
      if (compA > bA) bA = compA;
      if (compB > bB) bB = compB;
      if (compC > bC) bC = compC;
      if (compD > bD) bD = compD;
    }
    if (bB > bA) bA = bB;
    if (bC > bA) bA = bC;
    if (bD > bA) bA = bD;
    unsigned long long best = bA;
#pragma unroll
    for (int off = 32; off; off >>= 1) {
      unsigned long long o = __shfl_down(best, off);
      if (o > best) best = o;
    }
    if (lane == 0) sh.neg.wmax[wid] = best;
    __syncthreads();
    if (tid == 0) {
      best = sh.neg.wmax[0];
      for (int w = 1; w < 4; ++w) if (sh.neg.wmax[w] > best) best = sh.neg.wmax[w];
      negIdx[row] = best ? (int)(~(uint32_t)best) : -1;
    }
    __syncthreads();
  }
}

// ---------------------------------------------------------------------------
// Kernel 6: loss (r11 proven, verbatim). grid 2048.
// ---------------------------------------------------------------------------
__global__ __launch_bounds__(256) void loss_kernel(const float* __restrict__ F,
                                                   const uint16_t* __restrict__ Hb,
                                                   const int* __restrict__ posIdx,
                                                   const int* __restrict__ negIdx,
                                                   float2* __restrict__ lossPart) {
  __shared__ float2 part[4];
  int row = blockIdx.x * 4 + (threadIdx.x >> 6);
  int lane = threadIdx.x & 63;
  int p = posIdx[row], n = negIdx[row];
  bool valid = (p >= 0) && (n >= 0);
  int ps = valid ? p : row;
  int ns = valid ? n : row;
  int k = lane * 8;
  const float* Fi = F + (size_t)row * DIM + k;
  const float* Fp = F + (size_t)ps * DIM + k;
  const float* Fn = F + (size_t)ns * DIM + k;
  u16x8 h_i = *(const u16x8*)(Hb + (size_t)row * DIM + k);
  u16x8 h_p = *(const u16x8*)(Hb + (size_t)ps * DIM + k);
  u16x8 h_n = *(const u16x8*)(Hb + (size_t)ns * DIM + k);
  float4 fi0 = *(const float4*)&Fi[0], fi1 = *(const float4*)&Fi[4];
  float4 fp0 = *(const float4*)&Fp[0], fp1 = *(const float4*)&Fp[4];
  float4 fn0 = *(const float4*)&Fn[0], fn1 = *(const float4*)&Fn[4];
  float fi[8] = {fi0.x, fi0.y, fi0.z, fi0.w, fi1.x, fi1.y, fi1.z, fi1.w};
  float fp[8] = {fp0.x, fp0.y, fp0.z, fp0.w, fp1.x, fp1.y, fp1.z, fp1.w};
  float fn[8] = {fn0.x, fn0.y, fn0.z, fn0.w, fn1.x, fn1.y, fn1.z, fn1.w};
  float qii = 0.f, qpp = 0.f, qip = 0.f, qnn = 0.f, qin = 0.f;
#pragma unroll
  for (int jj = 0; jj < 8; ++jj) {
    float hi = bf2f(h_i[jj]), hp = bf2f(h_p[jj]), hn = bf2f(h_n[jj]);
    qii += fi[jj] * hi;
    qpp += fp[jj] * hp;
    qip += fi[jj] * hp;
    qnn += fn[jj] * hn;
    qin += fi[jj] * hn;
  }
#pragma unroll
  for (int off = 32; off > 0; off >>= 1) {
    qii += __shfl_down(qii, off);
    qpp += __shfl_down(qpp, off);
    qip += __shfl_down(qip, off);
    qnn += __shfl_down(qnn, off);
    qin += __shfl_down(qin, off);
  }
  if (lane == 0) {
    float d2p = fmaxf(qii + qpp - 2.f * qip, 0.f);
    float d2n = fmaxf(qii + qnn - 2.f * qin, 0.f);
    float v = fmaxf(sqrtf(d2p + 1e-8f) - sqrtf(d2n + 1e-8f) + 1.0f, 0.0f);
    if (!valid) v = 0.f;
    part[threadIdx.x >> 6] = make_float2(v, valid ? 1.f : 0.f);
  }
  __syncthreads();
  if (threadIdx.x == 0) {
    float s = 0.f, c = 0.f;
#pragma unroll
    for (int w = 0; w < 4; ++w) { s += part[w].x; c += part[w].y; }
    lossPart[blockIdx.x] = make_float2(s, c);
  }
}

// ---------------------------------------------------------------------------
// Kernel 7: finalize (r11 proven, verbatim).
// ---------------------------------------------------------------------------
__global__ __launch_bounds__(256) void finalize_kernel(const float2* __restrict__ lossPart,
                                                       float* __restrict__ out) {
  __shared__ float2 wsum[4];
  int tid = threadIdx.x;
  float s = 0.f, c = 0.f;
  for (int z = tid; z < 2048; z += 256) {
    float2 v = lossPart[z];
    s += v.x; c += v.y;
  }
#pragma unroll
  for (int off = 32; off > 0; off >>= 1) {
    s += __shfl_down(s, off);
    c += __shfl_down(c, off);
  }
  if ((tid & 63) == 0) wsum[tid >> 6] = make_float2(s, c);
  __syncthreads();
  if (tid == 0) {
    s = 0.f; c = 0.f;
#pragma unroll
    for (int w = 0; w < 4; ++w) { s += wsum[w].x; c += wsum[w].y; }
    out[0] = s / fmaxf(c, 1.0f);
  }
}

// ---------------------------------------------------------------------------
extern "C" void kernel_launch(void* const* d_in, const int* in_sizes, int n_in,
                              void* d_out, int out_size, void* d_ws, size_t ws_size,
                              hipStream_t stream) {
  const float* F = (const float*)d_in[0];
  const int* labels = (const int*)d_in[1];
  float* out = (float*)d_out;
  char* ws = (char*)d_ws;

  int* rowCtr    = (int*)(ws + OFF_CTR);
  float* S       = (float*)(ws + OFF_S);
  int* bStart    = (int*)(ws + OFF_BSTART);
  int* bIdx      = (int*)(ws + OFF_BIDX);
  int* posIdx    = (int*)(ws + OFF_PIDX);
  int* negIdx    = (int*)(ws + OFF_NIDX);
  float2* lPart  = (float2*)(ws + OFF_LPART);
  uint16_t* Gb   = (uint16_t*)(ws + OFF_GB);
  uint16_t* Fb   = (uint16_t*)(ws + OFF_FB);
  uint16_t* Hb   = (uint16_t*)(ws + OFF_HB);
  float* Mpart   = (float*)(ws + OFF_HB);   // consumed before Hb is written

  // Partitionable (foldlike) split of jax.random.key(42):
  uint32_t kp0, kp1, kn0, kn1;
  threefry2x32(0u, 42u, 0u, 0u, kp0, kp1);
  threefry2x32(0u, 42u, 0u, 1u, kn0, kn1);

  hipMemsetAsync(ws, 0, ZERO_BYTES, stream);

  prep_kernel<<<2048, 256, 0, stream>>>(F, Fb, S);

  dim3 covGrid(8, 8, 4);
  covmat_mfma_kernel<<<covGrid, 256, 0, stream>>>(Fb, Mpart);

  buildG_kernel<<<(DIM * DIM) / 256, 256, 0, stream>>>(Mpart, S, Gb);

  bucket_kernel<<<1, 256, 0, stream>>>(labels, bStart, bIdx);

  overlap_kernel<<<1024, 256, 0, stream>>>(Fb, Gb, Hb, labels, bStart, bIdx,
                                           posIdx, negIdx, rowCtr,
                                           kp0, kp1, kn0, kn1);

  loss_kernel<<<BSZ / 4, 256, 0, stream>>>(F, Hb, posIdx, negIdx, lPart);

  finalize_kernel<<<1, 256, 0, stream>>>(lPart, out);
}